// Round 1
// baseline (1705.275 us; speedup 1.0000x reference)
//
#include <hip/hip_runtime.h>

// EncoderBlock: B=8, S=2048, D=1024, H=4096, single-head attn (scale AFTER softmax),
// LN -> QKV -> scores -> softmax*(1/32) -> PV -> MLP(Swish) -> +residual.
// Round 1: correctness-first bf16 MFMA pipeline.
// Workspace requirement: ~191 MB (layout with liveness reuse below).

#define Bb_ 8
#define Ss_ 2048
#define Dd_ 1024
#define Hh_ 4096

typedef __bf16 bf16;
typedef __attribute__((ext_vector_type(8))) __bf16 bf16x8;
typedef __attribute__((ext_vector_type(4))) __bf16 bf16x4;
typedef __attribute__((ext_vector_type(4))) float f32x4;

enum { EPI_BF16 = 0, EPI_F32 = 1, EPI_SWISH = 2, EPI_RESID = 3 };

// ---------- transpose-cast: W[K][N] f32 -> WT[N][K] bf16 ----------
__global__ __launch_bounds__(256) void tcast_k(const float* __restrict__ W,
                                               bf16* __restrict__ WT, int K, int N) {
  __shared__ float tile[32][33];
  const int tn0 = blockIdx.x * 32;
  const int tk0 = blockIdx.y * 32;
  const int t = threadIdx.x;
  const int c = t & 31;
  const int r4 = t >> 5;  // 0..7
#pragma unroll
  for (int i = 0; i < 4; i++) {
    int r = r4 + i * 8;
    tile[r][c] = W[(long)(tk0 + r) * N + (tn0 + c)];
  }
  __syncthreads();
#pragma unroll
  for (int i = 0; i < 4; i++) {
    int r = r4 + i * 8;  // n within tile
    WT[(long)(tn0 + r) * K + (tk0 + c)] = (bf16)tile[c][r];
  }
}

// ---------- LayerNorm: x[row][1024] f32 -> xn bf16 ----------
__global__ __launch_bounds__(256) void ln_k(const float* __restrict__ x,
                                            const float* __restrict__ gamma,
                                            const float* __restrict__ beta,
                                            bf16* __restrict__ xn) {
  const long row = blockIdx.x;
  const float* xr = x + row * Dd_;
  const int t = threadIdx.x;
  float4 v = *(const float4*)(xr + t * 4);
  float s = v.x + v.y + v.z + v.w;
  float sq = v.x * v.x + v.y * v.y + v.z * v.z + v.w * v.w;
#pragma unroll
  for (int o = 32; o > 0; o >>= 1) {
    s += __shfl_down(s, o);
    sq += __shfl_down(sq, o);
  }
  __shared__ float ls[4], lq[4];
  const int wid = t >> 6;
  if ((t & 63) == 0) { ls[wid] = s; lq[wid] = sq; }
  __syncthreads();
  if (t == 0) {
    float S = ls[0] + ls[1] + ls[2] + ls[3];
    float Q = lq[0] + lq[1] + lq[2] + lq[3];
    float mu = S * (1.0f / Dd_);
    float var = Q * (1.0f / Dd_) - mu * mu;
    ls[0] = mu;
    lq[0] = rsqrtf(var + 1e-5f);
  }
  __syncthreads();
  const float mu = ls[0], rstd = lq[0];
  float4 g = *(const float4*)(gamma + t * 4);
  float4 be = *(const float4*)(beta + t * 4);
  bf16x4 ov;
  ov[0] = (bf16)((v.x - mu) * rstd * g.x + be.x);
  ov[1] = (bf16)((v.y - mu) * rstd * g.y + be.y);
  ov[2] = (bf16)((v.z - mu) * rstd * g.z + be.z);
  ov[3] = (bf16)((v.w - mu) * rstd * g.w + be.w);
  *(bf16x4*)(xn + row * Dd_ + t * 4) = ov;
}

// ---------- softmax row kernel: scores f32 [2048] -> atten bf16 * (1/32) ----------
__global__ __launch_bounds__(256) void softmax_k(const float* __restrict__ sc,
                                                 bf16* __restrict__ at) {
  const long row = blockIdx.x;
  const float* sr = sc + row * (long)Ss_;
  const int t = threadIdx.x;
  float4 v0 = *(const float4*)(sr + t * 8);
  float4 v1 = *(const float4*)(sr + t * 8 + 4);
  float vm = fmaxf(fmaxf(fmaxf(v0.x, v0.y), fmaxf(v0.z, v0.w)),
                   fmaxf(fmaxf(v1.x, v1.y), fmaxf(v1.z, v1.w)));
  __shared__ float red[4];
#pragma unroll
  for (int o = 32; o > 0; o >>= 1) vm = fmaxf(vm, __shfl_xor(vm, o));
  const int wid = t >> 6;
  if ((t & 63) == 0) red[wid] = vm;
  __syncthreads();
  vm = fmaxf(fmaxf(red[0], red[1]), fmaxf(red[2], red[3]));
  float e[8];
  e[0] = __expf(v0.x - vm); e[1] = __expf(v0.y - vm);
  e[2] = __expf(v0.z - vm); e[3] = __expf(v0.w - vm);
  e[4] = __expf(v1.x - vm); e[5] = __expf(v1.y - vm);
  e[6] = __expf(v1.z - vm); e[7] = __expf(v1.w - vm);
  float s = e[0] + e[1] + e[2] + e[3] + e[4] + e[5] + e[6] + e[7];
#pragma unroll
  for (int o = 32; o > 0; o >>= 1) s += __shfl_xor(s, o);
  __syncthreads();  // red[] reuse guard
  if ((t & 63) == 0) red[wid] = s;
  __syncthreads();
  s = red[0] + red[1] + red[2] + red[3];
  const float scale = 0.03125f / s;  // 1/sqrt(1024) folded in
  bf16x8 ov;
#pragma unroll
  for (int j = 0; j < 8; j++) ov[j] = (bf16)(e[j] * scale);
  *(bf16x8*)(at + row * (long)Ss_ + t * 8) = ov;
}

// ---------- GEMM: C[M][N] = A[M][K] * B, bf16 MFMA 16x16x32, 128x128x32 tile ----------
// BT=true : B is [N][K] row-major (k-contiguous)      -> cheap staging
// BT=false: B is [K][N] row-major (transposed in LDS) -> scatter staging
template <bool BT, int EPI>
__global__ __launch_bounds__(256) void gemm_k(
    const bf16* __restrict__ Ab, const bf16* __restrict__ Bbp, void* __restrict__ Cb,
    const float* __restrict__ bias, const float* __restrict__ resid,
    int M, int N, int K, int lda, int ldb, int ldc,
    long astr, long bstr, long cstr) {
  __shared__ bf16 As[128][40];  // 80B rows: 16B aligned, <=2-way bank conflict
  __shared__ bf16 Bs[128][40];  // Bs[n][k]
  const int t = threadIdx.x;
  const int lane = t & 63;
  const int wid = t >> 6;
  const int wm = wid >> 1, wn = wid & 1;
  const long z = blockIdx.z;
  const bf16* A = Ab + z * astr;
  const bf16* Bp = Bbp + z * bstr;
  const int m0 = blockIdx.y * 128;
  const int n0 = blockIdx.x * 128;

  f32x4 acc[4][4] = {};

  const int ar = t >> 2;         // 0..63 (row within half-tile)
  const int ac = (t & 3) * 8;    // k offset
  const int bk = t >> 4;         // 0..15 (k row, NN path)
  const int bn = (t & 15) * 8;   // n offset (NN path)
  const int fr = lane & 15;
  const int fk = (lane >> 4) * 8;

  for (int k0 = 0; k0 < K; k0 += 32) {
    bf16x8 a0 = *(const bf16x8*)(A + (long)(m0 + ar) * lda + (k0 + ac));
    bf16x8 a1 = *(const bf16x8*)(A + (long)(m0 + 64 + ar) * lda + (k0 + ac));
    bf16x8 b0, b1;
    if constexpr (BT) {
      b0 = *(const bf16x8*)(Bp + (long)(n0 + ar) * ldb + (k0 + ac));
      b1 = *(const bf16x8*)(Bp + (long)(n0 + 64 + ar) * ldb + (k0 + ac));
    } else {
      b0 = *(const bf16x8*)(Bp + (long)(k0 + bk) * ldb + (n0 + bn));
      b1 = *(const bf16x8*)(Bp + (long)(k0 + 16 + bk) * ldb + (n0 + bn));
    }
    __syncthreads();  // guard prev-iter fragment reads
    *(bf16x8*)&As[ar][ac] = a0;
    *(bf16x8*)&As[64 + ar][ac] = a1;
    if constexpr (BT) {
      *(bf16x8*)&Bs[ar][ac] = b0;
      *(bf16x8*)&Bs[64 + ar][ac] = b1;
    } else {
#pragma unroll
      for (int j = 0; j < 8; j++) {
        Bs[bn + j][bk] = b0[j];
        Bs[bn + j][16 + bk] = b1[j];
      }
    }
    __syncthreads();
    bf16x8 af[4], bfv[4];
#pragma unroll
    for (int i = 0; i < 4; i++) {
      af[i] = *(const bf16x8*)&As[wm * 64 + i * 16 + fr][fk];
      bfv[i] = *(const bf16x8*)&Bs[wn * 64 + i * 16 + fr][fk];
    }
#pragma unroll
    for (int mi = 0; mi < 4; mi++)
#pragma unroll
      for (int ni = 0; ni < 4; ni++)
        acc[mi][ni] =
            __builtin_amdgcn_mfma_f32_16x16x32_bf16(af[mi], bfv[ni], acc[mi][ni], 0, 0, 0);
  }

  // epilogue: C/D layout col=lane&15, row=(lane>>4)*4+j  [m89 verified]
  const int row0 = m0 + wm * 64;
  const int col0 = n0 + wn * 64;
  const int cl = lane & 15;
  const int rg = (lane >> 4) * 4;
#pragma unroll
  for (int mi = 0; mi < 4; mi++) {
#pragma unroll
    for (int ni = 0; ni < 4; ni++) {
#pragma unroll
      for (int j = 0; j < 4; j++) {
        const long gm = row0 + mi * 16 + rg + j;
        const int gn = col0 + ni * 16 + cl;
        float val = acc[mi][ni][j];
        if constexpr (EPI == EPI_BF16) {
          ((bf16*)Cb)[z * cstr + gm * ldc + gn] = (bf16)val;
        } else if constexpr (EPI == EPI_F32) {
          ((float*)Cb)[z * cstr + gm * ldc + gn] = val;
        } else if constexpr (EPI == EPI_SWISH) {
          float hv = val + bias[gn];
          ((bf16*)Cb)[z * cstr + gm * ldc + gn] = (bf16)(hv / (1.0f + __expf(-hv)));
        } else {  // EPI_RESID
          ((float*)Cb)[z * cstr + gm * ldc + gn] = val + bias[gn] + resid[gm * (long)ldc + gn];
        }
      }
    }
  }
}

extern "C" void kernel_launch(void* const* d_in, const int* in_sizes, int n_in,
                              void* d_out, int out_size, void* d_ws, size_t ws_size,
                              hipStream_t stream) {
  const float* x  = (const float*)d_in[0];
  const float* g  = (const float*)d_in[1];
  const float* be = (const float*)d_in[2];
  const float* Wq = (const float*)d_in[3];
  const float* Wk = (const float*)d_in[4];
  const float* Wv = (const float*)d_in[5];
  const float* W1 = (const float*)d_in[6];
  const float* b1 = (const float*)d_in[7];
  const float* W2 = (const float*)d_in[8];
  const float* b2 = (const float*)d_in[9];

  // ---- workspace layout (bytes); liveness-reused; total 190,840,832 ----
  char* ws = (char*)d_ws;
  bf16* xn   = (bf16*)(ws + 0);           // [16384][1024] dead after QKV
  bf16* q    = (bf16*)(ws + 33554432);    // [8][2048][1024]
  bf16* kk   = (bf16*)(ws + 67108864);
  bf16* v    = (bf16*)(ws + 100663296);
  bf16* ao   = (bf16*)(ws + 134217728);   // attn out [16384][1024]
  bf16* wqT  = (bf16*)(ws + 167772160);   // wq/wk/wv T, contiguous, stride 1024*1024
  bf16* w1T  = (bf16*)(ws + 174063616);   // [4096][1024]
  bf16* w2T  = (bf16*)(ws + 182452224);   // [1024][4096]
  float* scores = (float*)(ws + 0);        // per-batch [2048][2048] f32 (over dead xn)
  bf16* atten   = (bf16*)(ws + 16777216);  // per-batch [2048][2048] bf16
  bf16* h       = (bf16*)(ws + 0);         // [16384][4096] (over xn|q|k|v, exact fit)

  // weights -> bf16 transposed
  tcast_k<<<dim3(32, 32), 256, 0, stream>>>(Wq, wqT, 1024, 1024);
  tcast_k<<<dim3(32, 32), 256, 0, stream>>>(Wk, wqT + 1048576, 1024, 1024);
  tcast_k<<<dim3(32, 32), 256, 0, stream>>>(Wv, wqT + 2097152, 1024, 1024);
  tcast_k<<<dim3(128, 32), 256, 0, stream>>>(W1, w1T, 1024, 4096);
  tcast_k<<<dim3(32, 128), 256, 0, stream>>>(W2, w2T, 4096, 1024);

  ln_k<<<16384, 256, 0, stream>>>(x, g, be, xn);

  // QKV: z selects weight & output
  gemm_k<true, EPI_BF16><<<dim3(8, 128, 3), 256, 0, stream>>>(
      xn, wqT, q, nullptr, nullptr, 16384, 1024, 1024, 1024, 1024, 1024,
      0L, 1048576L, 16777216L);

  // attention, per batch (scores scratch reuse)
  for (int b = 0; b < 8; b++) {
    const bf16* qb = q + (long)b * 2097152;
    const bf16* kb = kk + (long)b * 2097152;
    const bf16* vb = v + (long)b * 2097152;
    bf16* aob = ao + (long)b * 2097152;
    gemm_k<true, EPI_F32><<<dim3(16, 16, 1), 256, 0, stream>>>(
        qb, kb, scores, nullptr, nullptr, 2048, 2048, 1024, 1024, 1024, 2048, 0L, 0L, 0L);
    softmax_k<<<2048, 256, 0, stream>>>(scores, atten);
    gemm_k<false, EPI_BF16><<<dim3(8, 16, 1), 256, 0, stream>>>(
        atten, vb, aob, nullptr, nullptr, 2048, 1024, 2048, 2048, 1024, 1024, 0L, 0L, 0L);
  }

  // MLP1: h = swish(ao @ W1 + b1)
  gemm_k<true, EPI_SWISH><<<dim3(32, 128, 1), 256, 0, stream>>>(
      ao, w1T, h, b1, nullptr, 16384, 4096, 1024, 1024, 1024, 4096, 0L, 0L, 0L);
  // MLP2: out = h @ W2 + b2 + x
  gemm_k<true, EPI_RESID><<<dim3(8, 128, 1), 256, 0, stream>>>(
      h, w2T, d_out, b2, x, 16384, 1024, 4096, 4096, 4096, 1024, 0L, 0L, 0L);
}

// Round 2
// 1040.396 us; speedup vs baseline: 1.6391x; 1.6391x over previous
//
#include <hip/hip_runtime.h>

// EncoderBlock: B=8, S=2048, D=1024, H=4096, single-head attn (scale AFTER softmax),
// LN -> QKV -> scores -> softmax*(1/32) -> PV -> MLP(Swish) -> +residual.
// Round 2: batched attention (grouped z), V pre-transpose, in-place softmax.
// Workspace: 190,840,832 B baseline layout (G=2); G=8 fast path if ws >= 358,612,992.

#define Bb_ 8
#define Ss_ 2048
#define Dd_ 1024
#define Hh_ 4096

typedef __bf16 bf16;
typedef __attribute__((ext_vector_type(8))) __bf16 bf16x8;
typedef __attribute__((ext_vector_type(4))) __bf16 bf16x4;
typedef __attribute__((ext_vector_type(4))) float f32x4;

enum { EPI_BF16 = 0, EPI_F32 = 1, EPI_SWISH = 2, EPI_RESID = 3 };

// ---------- transpose-cast: W[K][N] f32 -> WT[N][K] bf16 ----------
__global__ __launch_bounds__(256) void tcast_k(const float* __restrict__ W,
                                               bf16* __restrict__ WT, int K, int N) {
  __shared__ float tile[32][33];
  const int tn0 = blockIdx.x * 32;
  const int tk0 = blockIdx.y * 32;
  const int t = threadIdx.x;
  const int c = t & 31;
  const int r4 = t >> 5;  // 0..7
#pragma unroll
  for (int i = 0; i < 4; i++) {
    int r = r4 + i * 8;
    tile[r][c] = W[(long)(tk0 + r) * N + (tn0 + c)];
  }
  __syncthreads();
#pragma unroll
  for (int i = 0; i < 4; i++) {
    int r = r4 + i * 8;  // n within tile
    WT[(long)(tn0 + r) * K + (tk0 + c)] = (bf16)tile[c][r];
  }
}

// ---------- bf16 transpose: V[z][2048][1024] -> VT[z][1024][2048] ----------
__global__ __launch_bounds__(256) void tbf_k(const bf16* __restrict__ V,
                                             bf16* __restrict__ VT) {
  __shared__ bf16 tile[64][72];
  const long z = blockIdx.z;
  const int n0 = blockIdx.x * 64;  // col block in source (D dim)
  const int k0 = blockIdx.y * 64;  // row block in source (S dim)
  const int t = threadIdx.x;
  const int r = t >> 3;        // 0..31
  const int c = (t & 7) * 8;   // 0..56
  const bf16* Vb = V + z * (long)(Ss_ * Dd_);
  bf16* VTb = VT + z * (long)(Dd_ * Ss_);
#pragma unroll
  for (int i = 0; i < 2; i++)
    *(bf16x8*)&tile[r + i * 32][c] =
        *(const bf16x8*)(Vb + (long)(k0 + r + i * 32) * Dd_ + n0 + c);
  __syncthreads();
#pragma unroll
  for (int i = 0; i < 2; i++) {
    const int n = r + i * 32;
    bf16x8 ov;
#pragma unroll
    for (int j = 0; j < 8; j++) ov[j] = tile[c + j][n];
    *(bf16x8*)(VTb + (long)(n0 + n) * Ss_ + k0 + c) = ov;
  }
}

// ---------- LayerNorm: x[row][1024] f32 -> xn bf16 ----------
__global__ __launch_bounds__(256) void ln_k(const float* __restrict__ x,
                                            const float* __restrict__ gamma,
                                            const float* __restrict__ beta,
                                            bf16* __restrict__ xn) {
  const long row = blockIdx.x;
  const float* xr = x + row * Dd_;
  const int t = threadIdx.x;
  float4 v = *(const float4*)(xr + t * 4);
  float s = v.x + v.y + v.z + v.w;
  float sq = v.x * v.x + v.y * v.y + v.z * v.z + v.w * v.w;
#pragma unroll
  for (int o = 32; o > 0; o >>= 1) {
    s += __shfl_down(s, o);
    sq += __shfl_down(sq, o);
  }
  __shared__ float ls[4], lq[4];
  const int wid = t >> 6;
  if ((t & 63) == 0) { ls[wid] = s; lq[wid] = sq; }
  __syncthreads();
  if (t == 0) {
    float S = ls[0] + ls[1] + ls[2] + ls[3];
    float Q = lq[0] + lq[1] + lq[2] + lq[3];
    float mu = S * (1.0f / Dd_);
    float var = Q * (1.0f / Dd_) - mu * mu;
    ls[0] = mu;
    lq[0] = rsqrtf(var + 1e-5f);
  }
  __syncthreads();
  const float mu = ls[0], rstd = lq[0];
  float4 g = *(const float4*)(gamma + t * 4);
  float4 be = *(const float4*)(beta + t * 4);
  bf16x4 ov;
  ov[0] = (bf16)((v.x - mu) * rstd * g.x + be.x);
  ov[1] = (bf16)((v.y - mu) * rstd * g.y + be.y);
  ov[2] = (bf16)((v.z - mu) * rstd * g.z + be.z);
  ov[3] = (bf16)((v.w - mu) * rstd * g.w + be.w);
  *(bf16x4*)(xn + row * Dd_ + t * 4) = ov;
}

// ---------- softmax row: scores f32 [2048] -> bf16 * (1/32), IN PLACE ----------
// Writes bf16 result over the first half of the same f32 row (row stride stays
// 2048 f32 = 4096 bf16 elements). Loads complete before stores (barriers between).
__global__ __launch_bounds__(256) void softmax_k(float* __restrict__ sc) {
  const long row = blockIdx.x;
  float* sr = sc + row * (long)Ss_;
  const int t = threadIdx.x;
  float4 v0 = *(const float4*)(sr + t * 8);
  float4 v1 = *(const float4*)(sr + t * 8 + 4);
  float vm = fmaxf(fmaxf(fmaxf(v0.x, v0.y), fmaxf(v0.z, v0.w)),
                   fmaxf(fmaxf(v1.x, v1.y), fmaxf(v1.z, v1.w)));
  __shared__ float red[4];
#pragma unroll
  for (int o = 32; o > 0; o >>= 1) vm = fmaxf(vm, __shfl_xor(vm, o));
  const int wid = t >> 6;
  if ((t & 63) == 0) red[wid] = vm;
  __syncthreads();
  vm = fmaxf(fmaxf(red[0], red[1]), fmaxf(red[2], red[3]));
  float e[8];
  e[0] = __expf(v0.x - vm); e[1] = __expf(v0.y - vm);
  e[2] = __expf(v0.z - vm); e[3] = __expf(v0.w - vm);
  e[4] = __expf(v1.x - vm); e[5] = __expf(v1.y - vm);
  e[6] = __expf(v1.z - vm); e[7] = __expf(v1.w - vm);
  float s = e[0] + e[1] + e[2] + e[3] + e[4] + e[5] + e[6] + e[7];
#pragma unroll
  for (int o = 32; o > 0; o >>= 1) s += __shfl_xor(s, o);
  __syncthreads();  // red[] reuse guard; also orders all row loads before stores
  if ((t & 63) == 0) red[wid] = s;
  __syncthreads();
  s = red[0] + red[1] + red[2] + red[3];
  const float scale = 0.03125f / s;  // 1/sqrt(1024) folded in
  bf16x8 ov;
#pragma unroll
  for (int j = 0; j < 8; j++) ov[j] = (bf16)(e[j] * scale);
  *(bf16x8*)((bf16*)sr + t * 8) = ov;
}

// ---------- GEMM: C[M][N] = A[M][K] * B[N][K], bf16 MFMA 16x16x32, 128x128x32 ----------
template <int EPI>
__global__ __launch_bounds__(256) void gemm_k(
    const bf16* __restrict__ Ab, const bf16* __restrict__ Bbp, void* __restrict__ Cb,
    const float* __restrict__ bias, const float* __restrict__ resid,
    int M, int N, int K, int lda, int ldb, int ldc,
    long astr, long bstr, long cstr) {
  __shared__ bf16 As[128][40];  // 80B rows: 16B aligned, <=2-way bank conflict
  __shared__ bf16 Bs[128][40];  // Bs[n][k]
  const int t = threadIdx.x;
  const int lane = t & 63;
  const int wid = t >> 6;
  const int wm = wid >> 1, wn = wid & 1;
  const long z = blockIdx.z;
  const bf16* A = Ab + z * astr;
  const bf16* Bp = Bbp + z * bstr;
  const int m0 = blockIdx.y * 128;
  const int n0 = blockIdx.x * 128;

  f32x4 acc[4][4] = {};

  const int ar = t >> 2;       // 0..63
  const int ac = (t & 3) * 8;  // k offset
  const int fr = lane & 15;
  const int fk = (lane >> 4) * 8;

  for (int k0 = 0; k0 < K; k0 += 32) {
    bf16x8 a0 = *(const bf16x8*)(A + (long)(m0 + ar) * lda + (k0 + ac));
    bf16x8 a1 = *(const bf16x8*)(A + (long)(m0 + 64 + ar) * lda + (k0 + ac));
    bf16x8 b0 = *(const bf16x8*)(Bp + (long)(n0 + ar) * ldb + (k0 + ac));
    bf16x8 b1 = *(const bf16x8*)(Bp + (long)(n0 + 64 + ar) * ldb + (k0 + ac));
    __syncthreads();  // guard prev-iter fragment reads
    *(bf16x8*)&As[ar][ac] = a0;
    *(bf16x8*)&As[64 + ar][ac] = a1;
    *(bf16x8*)&Bs[ar][ac] = b0;
    *(bf16x8*)&Bs[64 + ar][ac] = b1;
    __syncthreads();
    bf16x8 af[4], bfv[4];
#pragma unroll
    for (int i = 0; i < 4; i++) {
      af[i] = *(const bf16x8*)&As[wm * 64 + i * 16 + fr][fk];
      bfv[i] = *(const bf16x8*)&Bs[wn * 64 + i * 16 + fr][fk];
    }
#pragma unroll
    for (int mi = 0; mi < 4; mi++)
#pragma unroll
      for (int ni = 0; ni < 4; ni++)
        acc[mi][ni] =
            __builtin_amdgcn_mfma_f32_16x16x32_bf16(af[mi], bfv[ni], acc[mi][ni], 0, 0, 0);
  }

  // epilogue: C/D layout col=lane&15, row=(lane>>4)*4+j  [m89 verified]
  const int row0 = m0 + wm * 64;
  const int col0 = n0 + wn * 64;
  const int cl = lane & 15;
  const int rg = (lane >> 4) * 4;
#pragma unroll
  for (int mi = 0; mi < 4; mi++) {
#pragma unroll
    for (int ni = 0; ni < 4; ni++) {
#pragma unroll
      for (int j = 0; j < 4; j++) {
        const long gm = row0 + mi * 16 + rg + j;
        const int gn = col0 + ni * 16 + cl;
        float val = acc[mi][ni][j];
        if constexpr (EPI == EPI_BF16) {
          ((bf16*)Cb)[z * cstr + gm * ldc + gn] = (bf16)val;
        } else if constexpr (EPI == EPI_F32) {
          ((float*)Cb)[z * cstr + gm * ldc + gn] = val;
        } else if constexpr (EPI == EPI_SWISH) {
          float hv = val + bias[gn];
          ((bf16*)Cb)[z * cstr + gm * ldc + gn] = (bf16)(hv / (1.0f + __expf(-hv)));
        } else {  // EPI_RESID
          ((float*)Cb)[z * cstr + gm * ldc + gn] = val + bias[gn] + resid[gm * (long)ldc + gn];
        }
      }
    }
  }
}

extern "C" void kernel_launch(void* const* d_in, const int* in_sizes, int n_in,
                              void* d_out, int out_size, void* d_ws, size_t ws_size,
                              hipStream_t stream) {
  const float* x  = (const float*)d_in[0];
  const float* g  = (const float*)d_in[1];
  const float* be = (const float*)d_in[2];
  const float* Wq = (const float*)d_in[3];
  const float* Wk = (const float*)d_in[4];
  const float* Wv = (const float*)d_in[5];
  const float* W1 = (const float*)d_in[6];
  const float* b1 = (const float*)d_in[7];
  const float* W2 = (const float*)d_in[8];
  const float* b2 = (const float*)d_in[9];

  // ---- workspace layout (bytes); liveness-reused; peak 190,840,832 (G=2) ----
  // [0,32M): xn (LN->QKV), then vT (QKV->PV), then h low part (MLP)
  // [32,64M): q   [64,96M): k   [96,128M): v, then scores group (G=2, exact fit)
  // [128,160M): ao   [160M..): weights.  h = [0,134217728) overlays all-dead regions.
  char* ws = (char*)d_ws;
  bf16* xn   = (bf16*)(ws + 0);
  bf16* vT   = (bf16*)(ws + 0);
  bf16* q    = (bf16*)(ws + 33554432);
  bf16* kk   = (bf16*)(ws + 67108864);
  bf16* v    = (bf16*)(ws + 100663296);
  bf16* ao   = (bf16*)(ws + 134217728);
  bf16* wqT  = (bf16*)(ws + 167772160);   // wq/wk/wv T, stride 1024*1024
  bf16* w1T  = (bf16*)(ws + 174063616);   // [4096][1024]
  bf16* w2T  = (bf16*)(ws + 182452224);   // [1024][4096]
  bf16* h    = (bf16*)(ws + 0);           // [16384][4096]

  // scores group buffer: G=8 high path if ws allows, else G=2 over dead v (exact fit)
  const int G = (ws_size >= 358612992u) ? 8 : 2;
  float* scores = (G == 8) ? (float*)(ws + 224395264) : (float*)(ws + 100663296);

  // weights -> bf16 transposed
  tcast_k<<<dim3(32, 32), 256, 0, stream>>>(Wq, wqT, 1024, 1024);
  tcast_k<<<dim3(32, 32), 256, 0, stream>>>(Wk, wqT + 1048576, 1024, 1024);
  tcast_k<<<dim3(32, 32), 256, 0, stream>>>(Wv, wqT + 2097152, 1024, 1024);
  tcast_k<<<dim3(128, 32), 256, 0, stream>>>(W1, w1T, 1024, 4096);
  tcast_k<<<dim3(32, 128), 256, 0, stream>>>(W2, w2T, 4096, 1024);

  ln_k<<<16384, 256, 0, stream>>>(x, g, be, xn);

  // QKV: z selects weight & output (q,k,v contiguous, stride 16,777,216 elems)
  gemm_k<EPI_BF16><<<dim3(8, 128, 3), 256, 0, stream>>>(
      xn, wqT, q, nullptr, nullptr, 16384, 1024, 1024, 1024, 1024, 1024,
      0L, 1048576L, 16777216L);

  // V -> VT (xn dead now; vT takes offset 0)
  tbf_k<<<dim3(16, 32, 8), 256, 0, stream>>>(v, vT);

  // attention in groups of G batches
  for (int g0 = 0; g0 < 8; g0 += G) {
    // scores[z] = q[g0+z] @ k[g0+z]^T   (f32, ldc=2048)
    gemm_k<EPI_F32><<<dim3(16, 16, G), 256, 0, stream>>>(
        q + (long)g0 * 2097152, kk + (long)g0 * 2097152, scores, nullptr, nullptr,
        2048, 2048, 1024, 1024, 1024, 2048, 2097152L, 2097152L, 4194304L);
    // softmax in place: f32 row -> bf16 half-row (*1/32)
    softmax_k<<<G * 2048, 256, 0, stream>>>(scores);
    // ao[g0+z] = atten[z] @ vT[g0+z]^T   (atten bf16, lda=4096)
    gemm_k<EPI_BF16><<<dim3(8, 16, G), 256, 0, stream>>>(
        (const bf16*)scores, vT + (long)g0 * 2097152, ao + (long)g0 * 2097152,
        nullptr, nullptr, 2048, 1024, 2048, 4096, 2048, 1024,
        8388608L, 2097152L, 2097152L);
  }

  // MLP1: h = swish(ao @ W1 + b1)
  gemm_k<EPI_SWISH><<<dim3(32, 128, 1), 256, 0, stream>>>(
      ao, w1T, h, b1, nullptr, 16384, 4096, 1024, 1024, 1024, 4096, 0L, 0L, 0L);
  // MLP2: out = h @ W2 + b2 + x
  gemm_k<EPI_RESID><<<dim3(8, 128, 1), 256, 0, stream>>>(
      h, w2T, d_out, b2, x, 16384, 1024, 4096, 4096, 4096, 1024, 0L, 0L, 0L);
}

// Round 3
// 1020.109 us; speedup vs baseline: 1.6717x; 1.0199x over previous
//
#include <hip/hip_runtime.h>

// EncoderBlock: B=8, S=2048, D=1024, H=4096, single-head attn (scale AFTER softmax),
// LN -> QKV -> scores -> softmax*(1/32) -> PV -> MLP(Swish) -> +residual.
// Round 3: m97-structure GEMM core (global_load_lds width=16, linear LDS, 2-barrier loop).
// Workspace: 190,840,832 B baseline layout (G=2); G=8 fast path if ws >= 358,612,992.

#define Bb_ 8
#define Ss_ 2048
#define Dd_ 1024
#define Hh_ 4096

typedef __bf16 bf16;
typedef __attribute__((ext_vector_type(8))) __bf16 bf16x8;
typedef __attribute__((ext_vector_type(4))) __bf16 bf16x4;
typedef __attribute__((ext_vector_type(4))) float f32x4;

enum { EPI_BF16 = 0, EPI_F32 = 1, EPI_SWISH = 2, EPI_RESID = 3 };

// async global->LDS, 16B per lane, wave-uniform LDS base (HW: base + lane*16)
__device__ __forceinline__ void gload16(const void* g, void* l) {
  __builtin_amdgcn_global_load_lds(
      (const __attribute__((address_space(1))) void*)g,
      (__attribute__((address_space(3))) void*)l, 16, 0, 0);
}

// ---------- transpose-cast: W[K][N] f32 -> WT[N][K] bf16 ----------
__global__ __launch_bounds__(256) void tcast_k(const float* __restrict__ W,
                                               bf16* __restrict__ WT, int K, int N) {
  __shared__ float tile[32][33];
  const int tn0 = blockIdx.x * 32;
  const int tk0 = blockIdx.y * 32;
  const int t = threadIdx.x;
  const int c = t & 31;
  const int r4 = t >> 5;  // 0..7
#pragma unroll
  for (int i = 0; i < 4; i++) {
    int r = r4 + i * 8;
    tile[r][c] = W[(long)(tk0 + r) * N + (tn0 + c)];
  }
  __syncthreads();
#pragma unroll
  for (int i = 0; i < 4; i++) {
    int r = r4 + i * 8;  // n within tile
    WT[(long)(tn0 + r) * K + (tk0 + c)] = (bf16)tile[c][r];
  }
}

// ---------- bf16 transpose: V[z][2048][1024] -> VT[z][1024][2048] ----------
__global__ __launch_bounds__(256) void tbf_k(const bf16* __restrict__ V,
                                             bf16* __restrict__ VT) {
  __shared__ bf16 tile[64][72];
  const long z = blockIdx.z;
  const int n0 = blockIdx.x * 64;  // col block in source (D dim)
  const int k0 = blockIdx.y * 64;  // row block in source (S dim)
  const int t = threadIdx.x;
  const int r = t >> 3;        // 0..31
  const int c = (t & 7) * 8;   // 0..56
  const bf16* Vb = V + z * (long)(Ss_ * Dd_);
  bf16* VTb = VT + z * (long)(Dd_ * Ss_);
#pragma unroll
  for (int i = 0; i < 2; i++)
    *(bf16x8*)&tile[r + i * 32][c] =
        *(const bf16x8*)(Vb + (long)(k0 + r + i * 32) * Dd_ + n0 + c);
  __syncthreads();
#pragma unroll
  for (int i = 0; i < 2; i++) {
    const int n = r + i * 32;
    bf16x8 ov;
#pragma unroll
    for (int j = 0; j < 8; j++) ov[j] = tile[c + j][n];
    *(bf16x8*)(VTb + (long)(n0 + n) * Ss_ + k0 + c) = ov;
  }
}

// ---------- LayerNorm: x[row][1024] f32 -> xn bf16 ----------
__global__ __launch_bounds__(256) void ln_k(const float* __restrict__ x,
                                            const float* __restrict__ gamma,
                                            const float* __restrict__ beta,
                                            bf16* __restrict__ xn) {
  const long row = blockIdx.x;
  const float* xr = x + row * Dd_;
  const int t = threadIdx.x;
  float4 v = *(const float4*)(xr + t * 4);
  float s = v.x + v.y + v.z + v.w;
  float sq = v.x * v.x + v.y * v.y + v.z * v.z + v.w * v.w;
#pragma unroll
  for (int o = 32; o > 0; o >>= 1) {
    s += __shfl_down(s, o);
    sq += __shfl_down(sq, o);
  }
  __shared__ float ls[4], lq[4];
  const int wid = t >> 6;
  if ((t & 63) == 0) { ls[wid] = s; lq[wid] = sq; }
  __syncthreads();
  if (t == 0) {
    float S = ls[0] + ls[1] + ls[2] + ls[3];
    float Q = lq[0] + lq[1] + lq[2] + lq[3];
    float mu = S * (1.0f / Dd_);
    float var = Q * (1.0f / Dd_) - mu * mu;
    ls[0] = mu;
    lq[0] = rsqrtf(var + 1e-5f);
  }
  __syncthreads();
  const float mu = ls[0], rstd = lq[0];
  float4 g = *(const float4*)(gamma + t * 4);
  float4 be = *(const float4*)(beta + t * 4);
  bf16x4 ov;
  ov[0] = (bf16)((v.x - mu) * rstd * g.x + be.x);
  ov[1] = (bf16)((v.y - mu) * rstd * g.y + be.y);
  ov[2] = (bf16)((v.z - mu) * rstd * g.z + be.z);
  ov[3] = (bf16)((v.w - mu) * rstd * g.w + be.w);
  *(bf16x4*)(xn + row * Dd_ + t * 4) = ov;
}

// ---------- softmax row: scores f32 [2048] -> bf16 * (1/32), IN PLACE ----------
__global__ __launch_bounds__(256) void softmax_k(float* __restrict__ sc) {
  const long row = blockIdx.x;
  float* sr = sc + row * (long)Ss_;
  const int t = threadIdx.x;
  float4 v0 = *(const float4*)(sr + t * 8);
  float4 v1 = *(const float4*)(sr + t * 8 + 4);
  float vm = fmaxf(fmaxf(fmaxf(v0.x, v0.y), fmaxf(v0.z, v0.w)),
                   fmaxf(fmaxf(v1.x, v1.y), fmaxf(v1.z, v1.w)));
  __shared__ float red[4];
#pragma unroll
  for (int o = 32; o > 0; o >>= 1) vm = fmaxf(vm, __shfl_xor(vm, o));
  const int wid = t >> 6;
  if ((t & 63) == 0) red[wid] = vm;
  __syncthreads();
  vm = fmaxf(fmaxf(red[0], red[1]), fmaxf(red[2], red[3]));
  float e[8];
  e[0] = __expf(v0.x - vm); e[1] = __expf(v0.y - vm);
  e[2] = __expf(v0.z - vm); e[3] = __expf(v0.w - vm);
  e[4] = __expf(v1.x - vm); e[5] = __expf(v1.y - vm);
  e[6] = __expf(v1.z - vm); e[7] = __expf(v1.w - vm);
  float s = e[0] + e[1] + e[2] + e[3] + e[4] + e[5] + e[6] + e[7];
#pragma unroll
  for (int o = 32; o > 0; o >>= 1) s += __shfl_xor(s, o);
  __syncthreads();  // red[] reuse guard; also orders all row loads before stores
  if ((t & 63) == 0) red[wid] = s;
  __syncthreads();
  s = red[0] + red[1] + red[2] + red[3];
  const float scale = 0.03125f / s;  // 1/sqrt(1024) folded in
  bf16x8 ov;
#pragma unroll
  for (int j = 0; j < 8; j++) ov[j] = (bf16)(e[j] * scale);
  *(bf16x8*)((bf16*)sr + t * 8) = ov;
}

// ---------- GEMM: C[M][N] = A[M][K] * B[N][K], m97 structure ----------
// 128x128x32 tile, 4 waves (2x2), global_load_lds width=16, linear LDS, 2 barriers/K-step.
template <int EPI>
__global__ __launch_bounds__(256) void gemm_k(
    const bf16* __restrict__ Ab, const bf16* __restrict__ Bbp, void* __restrict__ Cb,
    const float* __restrict__ bias, const float* __restrict__ resid,
    int M, int N, int K, int lda, int ldb, int ldc,
    long astr, long bstr, long cstr) {
  __shared__ bf16 As[128][32];  // linear: gload_lds writes base + lane*16
  __shared__ bf16 Bs[128][32];  // Bs[n][k]
  const int t = threadIdx.x;
  const int lane = t & 63;
  const int wid = t >> 6;
  const int wm = wid >> 1, wn = wid & 1;
  const long z = blockIdx.z;
  const bf16* A = Ab + z * astr;
  const bf16* Bp = Bbp + z * bstr;
  const int m0 = blockIdx.y * 128;
  const int n0 = blockIdx.x * 128;

  f32x4 acc[4][4] = {};

  // staging geometry: chunk c covers tile rows [16c,16c+16); wave w stages c=2w,2w+1.
  // lane l -> row 16c + (l>>2), k elems (l&3)*8 (LDS byte c*1024 + l*16, linear).
  const int c0 = wid * 2;
  const int sr0 = 16 * c0 + (lane >> 2);   // tile row for chunk c0
  const int sk = (lane & 3) * 8;           // k offset
  const int fr = lane & 15;
  const int fk = (lane >> 4) * 8;

  const bf16* Arow0 = A + (long)(m0 + sr0) * lda + sk;
  const bf16* Arow1 = A + (long)(m0 + sr0 + 16) * lda + sk;
  const bf16* Brow0 = Bp + (long)(n0 + sr0) * ldb + sk;
  const bf16* Brow1 = Bp + (long)(n0 + sr0 + 16) * ldb + sk;
  bf16* lA0 = &As[16 * c0][0];
  bf16* lA1 = &As[16 * (c0 + 1)][0];
  bf16* lB0 = &Bs[16 * c0][0];
  bf16* lB1 = &Bs[16 * (c0 + 1)][0];

  for (int k0 = 0; k0 < K; k0 += 32) {
    gload16(Arow0 + k0, lA0);
    gload16(Arow1 + k0, lA1);
    gload16(Brow0 + k0, lB0);
    gload16(Brow1 + k0, lB1);
    __syncthreads();  // drains vmcnt -> staged data visible
    bf16x8 af[4], bfv[4];
#pragma unroll
    for (int i = 0; i < 4; i++) {
      af[i] = *(const bf16x8*)&As[wm * 64 + i * 16 + fr][fk];
      bfv[i] = *(const bf16x8*)&Bs[wn * 64 + i * 16 + fr][fk];
    }
#pragma unroll
    for (int mi = 0; mi < 4; mi++)
#pragma unroll
      for (int ni = 0; ni < 4; ni++)
        acc[mi][ni] =
            __builtin_amdgcn_mfma_f32_16x16x32_bf16(af[mi], bfv[ni], acc[mi][ni], 0, 0, 0);
    __syncthreads();  // fragment reads done before next-iter overwrite
  }

  // epilogue: C/D layout col=lane&15, row=(lane>>4)*4+j  [m89 verified]
  const int row0 = m0 + wm * 64;
  const int col0 = n0 + wn * 64;
  const int cl = lane & 15;
  const int rg = (lane >> 4) * 4;
#pragma unroll
  for (int mi = 0; mi < 4; mi++) {
#pragma unroll
    for (int ni = 0; ni < 4; ni++) {
#pragma unroll
      for (int j = 0; j < 4; j++) {
        const long gm = row0 + mi * 16 + rg + j;
        const int gn = col0 + ni * 16 + cl;
        float val = acc[mi][ni][j];
        if constexpr (EPI == EPI_BF16) {
          ((bf16*)Cb)[z * cstr + gm * ldc + gn] = (bf16)val;
        } else if constexpr (EPI == EPI_F32) {
          ((float*)Cb)[z * cstr + gm * ldc + gn] = val;
        } else if constexpr (EPI == EPI_SWISH) {
          float hv = val + bias[gn];
          ((bf16*)Cb)[z * cstr + gm * ldc + gn] = (bf16)(hv / (1.0f + __expf(-hv)));
        } else {  // EPI_RESID
          ((float*)Cb)[z * cstr + gm * ldc + gn] = val + bias[gn] + resid[gm * (long)ldc + gn];
        }
      }
    }
  }
}

extern "C" void kernel_launch(void* const* d_in, const int* in_sizes, int n_in,
                              void* d_out, int out_size, void* d_ws, size_t ws_size,
                              hipStream_t stream) {
  const float* x  = (const float*)d_in[0];
  const float* g  = (const float*)d_in[1];
  const float* be = (const float*)d_in[2];
  const float* Wq = (const float*)d_in[3];
  const float* Wk = (const float*)d_in[4];
  const float* Wv = (const float*)d_in[5];
  const float* W1 = (const float*)d_in[6];
  const float* b1 = (const float*)d_in[7];
  const float* W2 = (const float*)d_in[8];
  const float* b2 = (const float*)d_in[9];

  // ---- workspace layout (bytes); liveness-reused; peak 190,840,832 (G=2) ----
  char* ws = (char*)d_ws;
  bf16* xn   = (bf16*)(ws + 0);
  bf16* vT   = (bf16*)(ws + 0);
  bf16* q    = (bf16*)(ws + 33554432);
  bf16* kk   = (bf16*)(ws + 67108864);
  bf16* v    = (bf16*)(ws + 100663296);
  bf16* ao   = (bf16*)(ws + 134217728);
  bf16* wqT  = (bf16*)(ws + 167772160);   // wq/wk/wv T, stride 1024*1024
  bf16* w1T  = (bf16*)(ws + 174063616);   // [4096][1024]
  bf16* w2T  = (bf16*)(ws + 182452224);   // [1024][4096]
  bf16* h    = (bf16*)(ws + 0);           // [16384][4096]

  const int G = (ws_size >= 358612992u) ? 8 : 2;
  float* scores = (G == 8) ? (float*)(ws + 224395264) : (float*)(ws + 100663296);

  // weights -> bf16 transposed
  tcast_k<<<dim3(32, 32), 256, 0, stream>>>(Wq, wqT, 1024, 1024);
  tcast_k<<<dim3(32, 32), 256, 0, stream>>>(Wk, wqT + 1048576, 1024, 1024);
  tcast_k<<<dim3(32, 32), 256, 0, stream>>>(Wv, wqT + 2097152, 1024, 1024);
  tcast_k<<<dim3(128, 32), 256, 0, stream>>>(W1, w1T, 1024, 4096);
  tcast_k<<<dim3(32, 128), 256, 0, stream>>>(W2, w2T, 4096, 1024);

  ln_k<<<16384, 256, 0, stream>>>(x, g, be, xn);

  // QKV: z selects weight & output (q,k,v contiguous, stride 16,777,216 elems)
  gemm_k<EPI_BF16><<<dim3(8, 128, 3), 256, 0, stream>>>(
      xn, wqT, q, nullptr, nullptr, 16384, 1024, 1024, 1024, 1024, 1024,
      0L, 1048576L, 16777216L);

  // V -> VT (xn dead now; vT takes offset 0)
  tbf_k<<<dim3(16, 32, 8), 256, 0, stream>>>(v, vT);

  // attention in groups of G batches
  for (int g0 = 0; g0 < 8; g0 += G) {
    gemm_k<EPI_F32><<<dim3(16, 16, G), 256, 0, stream>>>(
        q + (long)g0 * 2097152, kk + (long)g0 * 2097152, scores, nullptr, nullptr,
        2048, 2048, 1024, 1024, 1024, 2048, 2097152L, 2097152L, 4194304L);
    softmax_k<<<G * 2048, 256, 0, stream>>>(scores);
    gemm_k<EPI_BF16><<<dim3(8, 16, G), 256, 0, stream>>>(
        (const bf16*)scores, vT + (long)g0 * 2097152, ao + (long)g0 * 2097152,
        nullptr, nullptr, 2048, 1024, 2048, 4096, 2048, 1024,
        8388608L, 2097152L, 2097152L);
  }

  // MLP1: h = swish(ao @ W1 + b1)
  gemm_k<EPI_SWISH><<<dim3(32, 128, 1), 256, 0, stream>>>(
      ao, w1T, h, b1, nullptr, 16384, 4096, 1024, 1024, 1024, 4096, 0L, 0L, 0L);
  // MLP2: out = h @ W2 + b2 + x
  gemm_k<EPI_RESID><<<dim3(8, 128, 1), 256, 0, stream>>>(
      h, w2T, d_out, b2, x, 16384, 1024, 4096, 4096, 4096, 1024, 0L, 0L, 0L);
}

// Round 4
// 896.278 us; speedup vs baseline: 1.9026x; 1.1382x over previous
//
#include <hip/hip_runtime.h>

// EncoderBlock: B=8, S=2048, D=1024, H=4096, single-head attn (scale AFTER softmax),
// LN -> QKV -> scores -> softmax*(1/32) -> PV -> MLP(Swish) -> +residual.
// Round 4: 256x256 8-phase GEMM (T2 swizzle + T3/T4 counted vmcnt + T5 setprio + T1 XCD swizzle)
// for QKV/scores/MLP1/MLP2. PV stays on 128^2 kernel in the G=2 workspace path.

#define Bb_ 8
#define Ss_ 2048
#define Dd_ 1024
#define Hh_ 4096

typedef __bf16 bf16;
typedef __attribute__((ext_vector_type(8))) __bf16 bf16x8;
typedef __attribute__((ext_vector_type(4))) __bf16 bf16x4;
typedef __attribute__((ext_vector_type(4))) float f32x4;

enum { EPI_BF16 = 0, EPI_F32 = 1, EPI_SWISH = 2, EPI_RESID = 3 };

// async global->LDS, 16B per lane, wave-uniform LDS base (HW: base + lane*16)
__device__ __forceinline__ void gload16(const bf16* g, bf16* l) {
  __builtin_amdgcn_global_load_lds(
      (const __attribute__((address_space(1))) void*)g,
      (__attribute__((address_space(3))) void*)l, 16, 0, 0);
}

#define BAR() __builtin_amdgcn_s_barrier()
#define LGKM0() asm volatile("s_waitcnt lgkmcnt(0)" ::: "memory")
#define SETP(x) __builtin_amdgcn_s_setprio(x)

// ---------- transpose-cast: W[K][N] f32 -> WT[N][K] bf16 ----------
__global__ __launch_bounds__(256) void tcast_k(const float* __restrict__ W,
                                               bf16* __restrict__ WT, int K, int N) {
  __shared__ float tile[32][33];
  const int tn0 = blockIdx.x * 32;
  const int tk0 = blockIdx.y * 32;
  const int t = threadIdx.x;
  const int c = t & 31;
  const int r4 = t >> 5;
#pragma unroll
  for (int i = 0; i < 4; i++) {
    int r = r4 + i * 8;
    tile[r][c] = W[(long)(tk0 + r) * N + (tn0 + c)];
  }
  __syncthreads();
#pragma unroll
  for (int i = 0; i < 4; i++) {
    int r = r4 + i * 8;
    WT[(long)(tn0 + r) * K + (tk0 + c)] = (bf16)tile[c][r];
  }
}

// ---------- bf16 transpose: V[z][2048][1024] -> VT[z][1024][2048] ----------
__global__ __launch_bounds__(256) void tbf_k(const bf16* __restrict__ V,
                                             bf16* __restrict__ VT) {
  __shared__ bf16 tile[64][72];
  const long z = blockIdx.z;
  const int n0 = blockIdx.x * 64;
  const int k0 = blockIdx.y * 64;
  const int t = threadIdx.x;
  const int r = t >> 3;
  const int c = (t & 7) * 8;
  const bf16* Vb = V + z * (long)(Ss_ * Dd_);
  bf16* VTb = VT + z * (long)(Dd_ * Ss_);
#pragma unroll
  for (int i = 0; i < 2; i++)
    *(bf16x8*)&tile[r + i * 32][c] =
        *(const bf16x8*)(Vb + (long)(k0 + r + i * 32) * Dd_ + n0 + c);
  __syncthreads();
#pragma unroll
  for (int i = 0; i < 2; i++) {
    const int n = r + i * 32;
    bf16x8 ov;
#pragma unroll
    for (int j = 0; j < 8; j++) ov[j] = tile[c + j][n];
    *(bf16x8*)(VTb + (long)(n0 + n) * Ss_ + k0 + c) = ov;
  }
}

// ---------- LayerNorm: x[row][1024] f32 -> xn bf16 ----------
__global__ __launch_bounds__(256) void ln_k(const float* __restrict__ x,
                                            const float* __restrict__ gamma,
                                            const float* __restrict__ beta,
                                            bf16* __restrict__ xn) {
  const long row = blockIdx.x;
  const float* xr = x + row * Dd_;
  const int t = threadIdx.x;
  float4 v = *(const float4*)(xr + t * 4);
  float s = v.x + v.y + v.z + v.w;
  float sq = v.x * v.x + v.y * v.y + v.z * v.z + v.w * v.w;
#pragma unroll
  for (int o = 32; o > 0; o >>= 1) {
    s += __shfl_down(s, o);
    sq += __shfl_down(sq, o);
  }
  __shared__ float ls[4], lq[4];
  const int wid = t >> 6;
  if ((t & 63) == 0) { ls[wid] = s; lq[wid] = sq; }
  __syncthreads();
  if (t == 0) {
    float S = ls[0] + ls[1] + ls[2] + ls[3];
    float Q = lq[0] + lq[1] + lq[2] + lq[3];
    float mu = S * (1.0f / Dd_);
    float var = Q * (1.0f / Dd_) - mu * mu;
    ls[0] = mu;
    lq[0] = rsqrtf(var + 1e-5f);
  }
  __syncthreads();
  const float mu = ls[0], rstd = lq[0];
  float4 g = *(const float4*)(gamma + t * 4);
  float4 be = *(const float4*)(beta + t * 4);
  bf16x4 ov;
  ov[0] = (bf16)((v.x - mu) * rstd * g.x + be.x);
  ov[1] = (bf16)((v.y - mu) * rstd * g.y + be.y);
  ov[2] = (bf16)((v.z - mu) * rstd * g.z + be.z);
  ov[3] = (bf16)((v.w - mu) * rstd * g.w + be.w);
  *(bf16x4*)(xn + row * Dd_ + t * 4) = ov;
}

// ---------- softmax row: scores f32 [2048] -> bf16 * (1/32), IN PLACE ----------
__global__ __launch_bounds__(256) void softmax_k(float* __restrict__ sc) {
  const long row = blockIdx.x;
  float* sr = sc + row * (long)Ss_;
  const int t = threadIdx.x;
  float4 v0 = *(const float4*)(sr + t * 8);
  float4 v1 = *(const float4*)(sr + t * 8 + 4);
  float vm = fmaxf(fmaxf(fmaxf(v0.x, v0.y), fmaxf(v0.z, v0.w)),
                   fmaxf(fmaxf(v1.x, v1.y), fmaxf(v1.z, v1.w)));
  __shared__ float red[4];
#pragma unroll
  for (int o = 32; o > 0; o >>= 1) vm = fmaxf(vm, __shfl_xor(vm, o));
  const int wid = t >> 6;
  if ((t & 63) == 0) red[wid] = vm;
  __syncthreads();
  vm = fmaxf(fmaxf(red[0], red[1]), fmaxf(red[2], red[3]));
  float e[8];
  e[0] = __expf(v0.x - vm); e[1] = __expf(v0.y - vm);
  e[2] = __expf(v0.z - vm); e[3] = __expf(v0.w - vm);
  e[4] = __expf(v1.x - vm); e[5] = __expf(v1.y - vm);
  e[6] = __expf(v1.z - vm); e[7] = __expf(v1.w - vm);
  float s = e[0] + e[1] + e[2] + e[3] + e[4] + e[5] + e[6] + e[7];
#pragma unroll
  for (int o = 32; o > 0; o >>= 1) s += __shfl_xor(s, o);
  __syncthreads();
  if ((t & 63) == 0) red[wid] = s;
  __syncthreads();
  s = red[0] + red[1] + red[2] + red[3];
  const float scale = 0.03125f / s;
  bf16x8 ov;
#pragma unroll
  for (int j = 0; j < 8; j++) ov[j] = (bf16)(e[j] * scale);
  *(bf16x8*)((bf16*)sr + t * 8) = ov;
}

// ================= 256x256x64 8-phase GEMM (C = A[M][K] * B[N][K]^T) =================
// 512 thr = 8 waves (2M x 4N); wave tile 128x64; acc[8][4] 16x16x32 frags.
// LDS 128KiB dynamic: [buf2][A/B][half2][128*64] bf16; halves: A0=m0..127,A1=m128..255 etc.
// Swizzle: logical (r,k) stored at elem r*64 + (k ^ ((r&7)*8)); stage pre-swizzles the
// GLOBAL source (gload_lds dest is linear: chunk c=w*2+j rows [8c,8c+8), lane->row 8c+(l>>3),
// src col 8*((l&7)^(l>>3))).
// Schedule per iter (2 K-tiles t0=2i,t1=2i+1; buf0=even, buf1=odd):
//  P1 rdA03+B01(buf0) | stage buf1.A0<-t1 (i>0)  | MFMA Q00
//  P2 rdB23(buf0)     | stage buf1.A1<-t1 (i>0)  | MFMA Q01
//  P3 rdA47(buf0)     | stage buf0.B0<-t0+2      | MFMA Q10
//  P4                 | stage buf0.B1<-t0+2      | MFMA Q11 | vmcnt(4|0) pre-barrier
//  P5 rdA03+B01(buf1) | stage buf0.A0<-t0+2      | MFMA Q00
//  P6 rdB23(buf1)     | stage buf0.A1<-t0+2      | MFMA Q01
//  P7 rdA47(buf1)     | stage buf1.B0<-t1+2      | MFMA Q10
//  P8                 | stage buf1.B1<-t1+2      | MFMA Q11 | vmcnt(4) pre-barrier
// Hazards: every stage targets a half whose last ds_read was >=1 barrier earlier; the
// vmcnt(4) before the trailing barrier of P4/P8 guarantees (post-barrier, for ALL waves)
// the 4 oldest half-tiles have landed = exactly the halves the next reads consume.
template <int EPI>
__global__ __launch_bounds__(512, 2) void gemm8_k(
    const bf16* __restrict__ Ab, const bf16* __restrict__ Bbp, void* __restrict__ Cb,
    const float* __restrict__ bias, const float* __restrict__ resid,
    int K, int lda, int ldb, int ldc, long astr, long bstr, long cstr) {
  extern __shared__ bf16 L[];  // 2*2*2*8192 elems = 128 KiB
  const int t = threadIdx.x;
  const int lane = t & 63;
  const int w = t >> 6;
  const int wm = w >> 2, wn = w & 3;

  // bijective XCD swizzle (all grids have (gx*gy)%8==0)
  const int gx = gridDim.x;
  const int nwg = gx * gridDim.y;
  const int dd = blockIdx.y * gx + blockIdx.x;
  const int Lid = (dd & 7) * (nwg >> 3) + (dd >> 3);
  const int m0 = (Lid / gx) * 256;
  const int n0 = (Lid % gx) * 256;

  const long z = blockIdx.z;
  const bf16* A = Ab + z * astr;
  const bf16* Bp = Bbp + z * bstr;

  // staging source pointers [isB][half][j]
  const int sr0 = (w * 2 + 0) * 8 + (lane >> 3);
  const int sr1 = (w * 2 + 1) * 8 + (lane >> 3);
  const int sc = 8 * ((lane & 7) ^ (lane >> 3));
  const bf16* gS[2][2][2];
  gS[0][0][0] = A + (long)(m0 + sr0) * lda + sc;
  gS[0][0][1] = A + (long)(m0 + sr1) * lda + sc;
  gS[0][1][0] = A + (long)(m0 + 128 + sr0) * lda + sc;
  gS[0][1][1] = A + (long)(m0 + 128 + sr1) * lda + sc;
  gS[1][0][0] = Bp + (long)(n0 + sr0) * ldb + sc;
  gS[1][0][1] = Bp + (long)(n0 + sr1) * ldb + sc;
  gS[1][1][0] = Bp + (long)(n0 + 128 + sr0) * ldb + sc;
  gS[1][1][1] = Bp + (long)(n0 + 128 + sr1) * ldb + sc;

#define STAGE(buf, isB, half, tau)                                              \
  do {                                                                          \
    gload16(gS[isB][half][0] + (long)(tau)*64,                                  \
            &L[(((buf)*2 + (isB)) * 2 + (half)) * 8192 + w * 1024]);            \
    gload16(gS[isB][half][1] + (long)(tau)*64,                                  \
            &L[(((buf)*2 + (isB)) * 2 + (half)) * 8192 + w * 1024 + 512]);      \
  } while (0)

  // fragment read geometry
  const int rA = lane & 15;
  const int kk0 = (lane >> 4) * 8;
  const int xorv = (rA & 7) * 8;
  const int rB0 = (wn & 1) * 64 + rA;
  const int aB0 = (0 * 4 + wm) * 8192, aB1 = (1 * 4 + wm) * 8192;          // A section base per buf
  const int bB0 = (0 * 4 + 2 + (wn >> 1)) * 8192, bB1 = (1 * 4 + 2 + (wn >> 1)) * 8192;

#define READ_A(ab, mb)                                                          \
  _Pragma("unroll") for (int q_ = 0; q_ < 4; ++q_)                              \
  _Pragma("unroll") for (int ks_ = 0; ks_ < 2; ++ks_)                           \
      a[q_][ks_] = *(const bf16x8*)&L[(ab) + ((mb) * 16 + q_ * 16 + rA) * 64 +  \
                                      ((ks_ * 32 + kk0) ^ xorv)];
#define READ_B(bb, dst, nb)                                                     \
  _Pragma("unroll") for (int q_ = 0; q_ < 2; ++q_)                              \
  _Pragma("unroll") for (int ks_ = 0; ks_ < 2; ++ks_)                           \
      dst[q_][ks_] = *(const bf16x8*)&L[(bb) + (rB0 + ((nb) + q_) * 16) * 64 +  \
                                        ((ks_ * 32 + kk0) ^ xorv)];
#define QMFMA(mq, nq, bsel)                                                     \
  _Pragma("unroll") for (int m_ = 0; m_ < 4; ++m_)                              \
  _Pragma("unroll") for (int n_ = 0; n_ < 2; ++n_)                              \
  _Pragma("unroll") for (int ks_ = 0; ks_ < 2; ++ks_)                           \
      acc[(mq)*4 + m_][(nq)*2 + n_] = __builtin_amdgcn_mfma_f32_16x16x32_bf16(  \
          a[m_][ks_], bsel[n_][ks_], acc[(mq)*4 + m_][(nq)*2 + n_], 0, 0, 0);

  f32x4 acc[8][4] = {};
  bf16x8 a[4][2], b01[2][2], b23[2][2];

  // prologue: stage K-tiles 0 (buf0) and 1 (buf1) fully
  STAGE(0, 0, 0, 0); STAGE(0, 0, 1, 0); STAGE(0, 1, 0, 0); STAGE(0, 1, 1, 0);
  STAGE(1, 0, 0, 1); STAGE(1, 0, 1, 1); STAGE(1, 1, 0, 1); STAGE(1, 1, 1, 1);
  asm volatile("s_waitcnt vmcnt(8)" ::: "memory");
  BAR();

  const int NI = K >> 7;  // 2 K-tiles (2*64) per iteration
  for (int i = 0; i < NI; ++i) {
    const int t1 = 2 * i + 1;
    const bool nf = (i + 1 < NI);
    // P1
    READ_A(aB0, 0); READ_B(bB0, b01, 0);
    if (i > 0) STAGE(1, 0, 0, t1);
    BAR(); LGKM0(); SETP(1); QMFMA(0, 0, b01); SETP(0); BAR();
    // P2
    READ_B(bB0, b23, 2);
    if (i > 0) STAGE(1, 0, 1, t1);
    BAR(); LGKM0(); SETP(1); QMFMA(0, 1, b23); SETP(0); BAR();
    // P3
    READ_A(aB0, 4);
    if (nf) STAGE(0, 1, 0, t1 + 1);
    BAR(); LGKM0(); SETP(1); QMFMA(1, 0, b01); SETP(0); BAR();
    // P4
    if (nf) STAGE(0, 1, 1, t1 + 1);
    BAR(); SETP(1); QMFMA(1, 1, b23); SETP(0);
    if (nf) asm volatile("s_waitcnt vmcnt(4)" ::: "memory");
    else    asm volatile("s_waitcnt vmcnt(0)" ::: "memory");
    BAR();
    // P5
    READ_A(aB1, 0); READ_B(bB1, b01, 0);
    if (nf) STAGE(0, 0, 0, t1 + 1);
    BAR(); LGKM0(); SETP(1); QMFMA(0, 0, b01); SETP(0); BAR();
    // P6
    READ_B(bB1, b23, 2);
    if (nf) STAGE(0, 0, 1, t1 + 1);
    BAR(); LGKM0(); SETP(1); QMFMA(0, 1, b23); SETP(0); BAR();
    // P7
    READ_A(aB1, 4);
    if (nf) STAGE(1, 1, 0, t1 + 2);
    BAR(); LGKM0(); SETP(1); QMFMA(1, 0, b01); SETP(0); BAR();
    // P8
    if (nf) STAGE(1, 1, 1, t1 + 2);
    BAR(); SETP(1); QMFMA(1, 1, b23); SETP(0);
    if (nf) asm volatile("s_waitcnt vmcnt(4)" ::: "memory");
    BAR();
  }

  // epilogue: C/D layout col=lane&15, row=(lane>>4)*4+j
  const int row0 = m0 + wm * 128;
  const int col0 = n0 + wn * 64;
  const int cl = lane & 15;
  const int rg = (lane >> 4) * 4;
#pragma unroll
  for (int mi = 0; mi < 8; mi++) {
#pragma unroll
    for (int ni = 0; ni < 4; ni++) {
#pragma unroll
      for (int j = 0; j < 4; j++) {
        const long gm = row0 + mi * 16 + rg + j;
        const int gn = col0 + ni * 16 + cl;
        float val = acc[mi][ni][j];
        if constexpr (EPI == EPI_BF16) {
          ((bf16*)Cb)[z * cstr + gm * ldc + gn] = (bf16)val;
        } else if constexpr (EPI == EPI_F32) {
          ((float*)Cb)[z * cstr + gm * ldc + gn] = val;
        } else if constexpr (EPI == EPI_SWISH) {
          float hv = val + bias[gn];
          ((bf16*)Cb)[z * cstr + gm * ldc + gn] = (bf16)(hv / (1.0f + __expf(-hv)));
        } else {
          ((float*)Cb)[z * cstr + gm * ldc + gn] = val + bias[gn] + resid[gm * (long)ldc + gn];
        }
      }
    }
  }
#undef STAGE
#undef READ_A
#undef READ_B
#undef QMFMA
}

// ---------- 128x128x32 2-phase GEMM (kept for PV on the G=2 path) ----------
template <int EPI>
__global__ __launch_bounds__(256) void gemm_k(
    const bf16* __restrict__ Ab, const bf16* __restrict__ Bbp, void* __restrict__ Cb,
    const float* __restrict__ bias, const float* __restrict__ resid,
    int M, int N, int K, int lda, int ldb, int ldc,
    long astr, long bstr, long cstr) {
  __shared__ bf16 As[128][32];
  __shared__ bf16 Bs[128][32];
  const int t = threadIdx.x;
  const int lane = t & 63;
  const int wid = t >> 6;
  const int wm = wid >> 1, wn = wid & 1;
  const long z = blockIdx.z;
  const bf16* A = Ab + z * astr;
  const bf16* Bp = Bbp + z * bstr;
  const int m0 = blockIdx.y * 128;
  const int n0 = blockIdx.x * 128;

  f32x4 acc[4][4] = {};
  const int c0 = wid * 2;
  const int sr0 = 16 * c0 + (lane >> 2);
  const int sk = (lane & 3) * 8;
  const int fr = lane & 15;
  const int fk = (lane >> 4) * 8;

  const bf16* Arow0 = A + (long)(m0 + sr0) * lda + sk;
  const bf16* Arow1 = A + (long)(m0 + sr0 + 16) * lda + sk;
  const bf16* Brow0 = Bp + (long)(n0 + sr0) * ldb + sk;
  const bf16* Brow1 = Bp + (long)(n0 + sr0 + 16) * ldb + sk;
  bf16* lA0 = &As[16 * c0][0];
  bf16* lA1 = &As[16 * (c0 + 1)][0];
  bf16* lB0 = &Bs[16 * c0][0];
  bf16* lB1 = &Bs[16 * (c0 + 1)][0];

  for (int k0 = 0; k0 < K; k0 += 32) {
    gload16(Arow0 + k0, lA0);
    gload16(Arow1 + k0, lA1);
    gload16(Brow0 + k0, lB0);
    gload16(Brow1 + k0, lB1);
    __syncthreads();
    bf16x8 af[4], bfv[4];
#pragma unroll
    for (int i = 0; i < 4; i++) {
      af[i] = *(const bf16x8*)&As[wm * 64 + i * 16 + fr][fk];
      bfv[i] = *(const bf16x8*)&Bs[wn * 64 + i * 16 + fr][fk];
    }
#pragma unroll
    for (int mi = 0; mi < 4; mi++)
#pragma unroll
      for (int ni = 0; ni < 4; ni++)
        acc[mi][ni] =
            __builtin_amdgcn_mfma_f32_16x16x32_bf16(af[mi], bfv[ni], acc[mi][ni], 0, 0, 0);
    __syncthreads();
  }

  const int row0 = m0 + wm * 64;
  const int col0 = n0 + wn * 64;
  const int cl = lane & 15;
  const int rg = (lane >> 4) * 4;
#pragma unroll
  for (int mi = 0; mi < 4; mi++) {
#pragma unroll
    for (int ni = 0; ni < 4; ni++) {
#pragma unroll
      for (int j = 0; j < 4; j++) {
        const long gm = row0 + mi * 16 + rg + j;
        const int gn = col0 + ni * 16 + cl;
        float val = acc[mi][ni][j];
        if constexpr (EPI == EPI_BF16) {
          ((bf16*)Cb)[z * cstr + gm * ldc + gn] = (bf16)val;
        } else if constexpr (EPI == EPI_F32) {
          ((float*)Cb)[z * cstr + gm * ldc + gn] = val;
        } else if constexpr (EPI == EPI_SWISH) {
          float hv = val + bias[gn];
          ((bf16*)Cb)[z * cstr + gm * ldc + gn] = (bf16)(hv / (1.0f + __expf(-hv)));
        } else {
          ((float*)Cb)[z * cstr + gm * ldc + gn] = val + bias[gn] + resid[gm * (long)ldc + gn];
        }
      }
    }
  }
}

extern "C" void kernel_launch(void* const* d_in, const int* in_sizes, int n_in,
                              void* d_out, int out_size, void* d_ws, size_t ws_size,
                              hipStream_t stream) {
  const float* x  = (const float*)d_in[0];
  const float* g  = (const float*)d_in[1];
  const float* be = (const float*)d_in[2];
  const float* Wq = (const float*)d_in[3];
  const float* Wk = (const float*)d_in[4];
  const float* Wv = (const float*)d_in[5];
  const float* W1 = (const float*)d_in[6];
  const float* b1 = (const float*)d_in[7];
  const float* W2 = (const float*)d_in[8];
  const float* b2 = (const float*)d_in[9];

  // allow 128 KiB dynamic LDS for the 8-phase kernels (idempotent; capture-safe)
  hipFuncSetAttribute((const void*)&gemm8_k<EPI_BF16>,
                      hipFuncAttributeMaxDynamicSharedMemorySize, 131072);
  hipFuncSetAttribute((const void*)&gemm8_k<EPI_F32>,
                      hipFuncAttributeMaxDynamicSharedMemorySize, 131072);
  hipFuncSetAttribute((const void*)&gemm8_k<EPI_SWISH>,
                      hipFuncAttributeMaxDynamicSharedMemorySize, 131072);
  hipFuncSetAttribute((const void*)&gemm8_k<EPI_RESID>,
                      hipFuncAttributeMaxDynamicSharedMemorySize, 131072);

  // ---- workspace layout (bytes); liveness-reused; peak 190,840,832 (G=2) ----
  char* ws = (char*)d_ws;
  bf16* xn   = (bf16*)(ws + 0);
  bf16* vT   = (bf16*)(ws + 0);
  bf16* q    = (bf16*)(ws + 33554432);
  bf16* kk   = (bf16*)(ws + 67108864);
  bf16* v    = (bf16*)(ws + 100663296);
  bf16* ao   = (bf16*)(ws + 134217728);
  bf16* wqT  = (bf16*)(ws + 167772160);
  bf16* w1T  = (bf16*)(ws + 174063616);
  bf16* w2T  = (bf16*)(ws + 182452224);
  bf16* h    = (bf16*)(ws + 0);

  const int G = (ws_size >= 358612992u) ? 8 : 2;
  float* scores = (G == 8) ? (float*)(ws + 224395264) : (float*)(ws + 100663296);

  tcast_k<<<dim3(32, 32), 256, 0, stream>>>(Wq, wqT, 1024, 1024);
  tcast_k<<<dim3(32, 32), 256, 0, stream>>>(Wk, wqT + 1048576, 1024, 1024);
  tcast_k<<<dim3(32, 32), 256, 0, stream>>>(Wv, wqT + 2097152, 1024, 1024);
  tcast_k<<<dim3(128, 32), 256, 0, stream>>>(W1, w1T, 1024, 4096);
  tcast_k<<<dim3(32, 128), 256, 0, stream>>>(W2, w2T, 4096, 1024);

  ln_k<<<16384, 256, 0, stream>>>(x, g, be, xn);

  // QKV: [16384,1024] x [1024,1024]^T, z = weight select
  gemm8_k<EPI_BF16><<<dim3(4, 64, 3), 512, 131072, stream>>>(
      xn, wqT, q, nullptr, nullptr, 1024, 1024, 1024, 1024,
      0L, 1048576L, 16777216L);

  tbf_k<<<dim3(16, 32, 8), 256, 0, stream>>>(v, vT);

  for (int g0 = 0; g0 < 8; g0 += G) {
    // scores[z] = q @ k^T (f32, in-group z)
    gemm8_k<EPI_F32><<<dim3(8, 8, G), 512, 131072, stream>>>(
        q + (long)g0 * 2097152, kk + (long)g0 * 2097152, scores, nullptr, nullptr,
        1024, 1024, 1024, 2048, 2097152L, 2097152L, 4194304L);
    softmax_k<<<G * 2048, 256, 0, stream>>>(scores);
    // ao = atten @ vT^T (atten bf16 rows inside f32 scores buffer, lda=4096)
    if (G == 8) {
      gemm8_k<EPI_BF16><<<dim3(4, 8, 8), 512, 131072, stream>>>(
          (const bf16*)scores, vT, ao, nullptr, nullptr,
          2048, 4096, 2048, 1024, 8388608L, 2097152L, 2097152L);
    } else {
      gemm_k<EPI_BF16><<<dim3(8, 16, 2), 256, 0, stream>>>(
          (const bf16*)scores, vT + (long)g0 * 2097152, ao + (long)g0 * 2097152,
          nullptr, nullptr, 2048, 1024, 2048, 4096, 2048, 1024,
          8388608L, 2097152L, 2097152L);
    }
  }

  // MLP1: h = swish(ao @ W1 + b1)
  gemm8_k<EPI_SWISH><<<dim3(16, 64, 1), 512, 131072, stream>>>(
      ao, w1T, h, b1, nullptr, 1024, 1024, 1024, 4096, 0L, 0L, 0L);
  // MLP2: out = h @ W2 + b2 + x
  gemm8_k<EPI_RESID><<<dim3(4, 64, 1), 512, 131072, stream>>>(
      h, w2T, d_out, b2, x, 4096, 4096, 4096, 1024, 0L, 0L, 0L);
}

// Round 5
// 847.334 us; speedup vs baseline: 2.0125x; 1.0578x over previous
//
#include <hip/hip_runtime.h>

// EncoderBlock: B=8, S=2048, D=1024, H=4096, single-head attn (scale AFTER softmax),
// LN -> QKV -> scores -> softmax*(1/32) -> PV -> MLP(Swish) -> +residual.
// Round 5: asm-pinned 8-phase gemm8 (inline-asm ds_read_b128 + lgkmcnt + sched_barrier),
// branch-free fp16 attention (scores/probs fp16, V written transposed-fp16 by QKV epilogue,
// 1/32 folded into PV epilogue). Workspace: exactly 190,840,832 B, liveness-reused.

#define Bb_ 8
#define Ss_ 2048
#define Dd_ 1024
#define Hh_ 4096

typedef __bf16 bf16;
typedef _Float16 f16;
typedef __attribute__((ext_vector_type(8))) __bf16 bf16x8;
typedef __attribute__((ext_vector_type(8))) _Float16 f16x8;
typedef __attribute__((ext_vector_type(4))) __bf16 bf16x4;
typedef __attribute__((ext_vector_type(4))) float f32x4;

enum { EPI_QKV = 0, EPI_F16 = 1, EPI_AOS = 2, EPI_SWISH = 3, EPI_RESID = 4 };

// async global->LDS, 16B per lane, wave-uniform LDS base (HW: base + lane*16)
__device__ __forceinline__ void gload16(const bf16* g, bf16* l) {
  __builtin_amdgcn_global_load_lds(
      (const __attribute__((address_space(1))) void*)g,
      (__attribute__((address_space(3))) void*)l, 16, 0, 0);
}

typedef const __attribute__((address_space(3))) bf16 cl_bf16;
// inline-asm LDS read: invisible to the memory legalizer (no auto vmcnt stalls);
// ordering vs MFMA enforced manually via lgkmcnt(0)+sched_barrier(0) (rule #18).
__device__ __forceinline__ bf16x8 dsr128(const bf16* p) {
  bf16x8 r;
  asm volatile("ds_read_b128 %0, %1" : "=v"(r) : "v"((cl_bf16*)p));
  return r;
}

#define BAR() __builtin_amdgcn_s_barrier()
#define LGKM0() asm volatile("s_waitcnt lgkmcnt(0)" ::: "memory")
#define SCHED0() __builtin_amdgcn_sched_barrier(0)
#define SETP(x) __builtin_amdgcn_s_setprio(x)

// ---------- transpose-cast: W[K][N] f32 -> WT[N][K] bf16 ----------
__global__ __launch_bounds__(256) void tcast_k(const float* __restrict__ W,
                                               bf16* __restrict__ WT, int K, int N) {
  __shared__ float tile[32][33];
  const int tn0 = blockIdx.x * 32;
  const int tk0 = blockIdx.y * 32;
  const int t = threadIdx.x;
  const int c = t & 31;
  const int r4 = t >> 5;
#pragma unroll
  for (int i = 0; i < 4; i++) {
    int r = r4 + i * 8;
    tile[r][c] = W[(long)(tk0 + r) * N + (tn0 + c)];
  }
  __syncthreads();
#pragma unroll
  for (int i = 0; i < 4; i++) {
    int r = r4 + i * 8;
    WT[(long)(tn0 + r) * K + (tk0 + c)] = (bf16)tile[c][r];
  }
}

// ---------- LayerNorm: x[row][1024] f32 -> xn bf16 ----------
__global__ __launch_bounds__(256) void ln_k(const float* __restrict__ x,
                                            const float* __restrict__ gamma,
                                            const float* __restrict__ beta,
                                            bf16* __restrict__ xn) {
  const long row = blockIdx.x;
  const float* xr = x + row * Dd_;
  const int t = threadIdx.x;
  float4 v = *(const float4*)(xr + t * 4);
  float s = v.x + v.y + v.z + v.w;
  float sq = v.x * v.x + v.y * v.y + v.z * v.z + v.w * v.w;
#pragma unroll
  for (int o = 32; o > 0; o >>= 1) {
    s += __shfl_down(s, o);
    sq += __shfl_down(sq, o);
  }
  __shared__ float ls[4], lq[4];
  const int wid = t >> 6;
  if ((t & 63) == 0) { ls[wid] = s; lq[wid] = sq; }
  __syncthreads();
  if (t == 0) {
    float S = ls[0] + ls[1] + ls[2] + ls[3];
    float Q = lq[0] + lq[1] + lq[2] + lq[3];
    float mu = S * (1.0f / Dd_);
    float var = Q * (1.0f / Dd_) - mu * mu;
    ls[0] = mu;
    lq[0] = rsqrtf(var + 1e-5f);
  }
  __syncthreads();
  const float mu = ls[0], rstd = lq[0];
  float4 g = *(const float4*)(gamma + t * 4);
  float4 be = *(const float4*)(beta + t * 4);
  bf16x4 ov;
  ov[0] = (bf16)((v.x - mu) * rstd * g.x + be.x);
  ov[1] = (bf16)((v.y - mu) * rstd * g.y + be.y);
  ov[2] = (bf16)((v.z - mu) * rstd * g.z + be.z);
  ov[3] = (bf16)((v.w - mu) * rstd * g.w + be.w);
  *(bf16x4*)(xn + row * Dd_ + t * 4) = ov;
}

// ---------- softmax row: scores f16 [2048] -> probs f16 (UNSCALED), in place ----------
__global__ __launch_bounds__(256) void softmax16_k(f16* __restrict__ sc) {
  const long row = blockIdx.x;
  f16* sr = sc + row * (long)Ss_;
  const int t = threadIdx.x;
  f16x8 v = *(const f16x8*)(sr + t * 8);
  float f[8];
#pragma unroll
  for (int j = 0; j < 8; j++) f[j] = (float)v[j];
  float vm = f[0];
#pragma unroll
  for (int j = 1; j < 8; j++) vm = fmaxf(vm, f[j]);
  __shared__ float red[4];
#pragma unroll
  for (int o = 32; o > 0; o >>= 1) vm = fmaxf(vm, __shfl_xor(vm, o));
  const int wid = t >> 6;
  if ((t & 63) == 0) red[wid] = vm;
  __syncthreads();
  vm = fmaxf(fmaxf(red[0], red[1]), fmaxf(red[2], red[3]));
  float e[8], s = 0.f;
#pragma unroll
  for (int j = 0; j < 8; j++) { e[j] = __expf(f[j] - vm); s += e[j]; }
#pragma unroll
  for (int o = 32; o > 0; o >>= 1) s += __shfl_xor(s, o);
  __syncthreads();
  if ((t & 63) == 0) red[wid] = s;
  __syncthreads();
  s = red[0] + red[1] + red[2] + red[3];
  const float rs = 1.0f / s;  // NOTE: 1/32 applied in PV epilogue (avoids f16 subnormals)
  f16x8 ov;
#pragma unroll
  for (int j = 0; j < 8; j++) ov[j] = (f16)(e[j] * rs);
  *(f16x8*)(sr + t * 8) = ov;
}

// ================= 256x256x64 8-phase GEMM (C = A[M][K] * B[N][K]^T) =================
// 512 thr = 8 waves (2M x 4N); wave tile 128x64; acc[8][4] 16x16x32 frags.
// DT=0: bf16 MFMA; DT=1: f16 MFMA (data staged as raw bytes either way).
// LDS 128KiB dynamic; st-swizzle: (r,k) at elem r*64 + (k ^ ((r&7)*8)); staged via
// pre-swizzled GLOBAL source + linear gload_lds dest (rule 21).
// Schedule: see R4 comments; vmcnt(4) only at phases 4/8 (counted, never 0 mid-loop).
template <int EPI, int DT>
__global__ __launch_bounds__(512, 2) void gemm8_k(
    const bf16* __restrict__ Ab, const bf16* __restrict__ Bbp, void* __restrict__ Cb,
    const float* __restrict__ bias, const float* __restrict__ resid,
    int K, int lda, int ldb, int ldc, long astr, long bstr, long cstr) {
  extern __shared__ bf16 L[];  // 2*2*2*8192 elems = 128 KiB
  const int t = threadIdx.x;
  const int lane = t & 63;
  const int w = t >> 6;
  const int wm = w >> 2, wn = w & 3;

  // bijective XCD swizzle (all grids have (gx*gy)%8==0)
  const int gx = gridDim.x;
  const int nwg = gx * gridDim.y;
  const int dd = blockIdx.y * gx + blockIdx.x;
  const int Lid = (dd & 7) * (nwg >> 3) + (dd >> 3);
  const int m0 = (Lid / gx) * 256;
  const int n0 = (Lid % gx) * 256;

  const long z = blockIdx.z;
  const bf16* A = Ab + z * astr;
  const bf16* Bp = Bbp + z * bstr;

  const int sr0 = (w * 2 + 0) * 8 + (lane >> 3);
  const int sr1 = (w * 2 + 1) * 8 + (lane >> 3);
  const int sc = 8 * ((lane & 7) ^ (lane >> 3));
  const bf16* gS[2][2][2];
  gS[0][0][0] = A + (long)(m0 + sr0) * lda + sc;
  gS[0][0][1] = A + (long)(m0 + sr1) * lda + sc;
  gS[0][1][0] = A + (long)(m0 + 128 + sr0) * lda + sc;
  gS[0][1][1] = A + (long)(m0 + 128 + sr1) * lda + sc;
  gS[1][0][0] = Bp + (long)(n0 + sr0) * ldb + sc;
  gS[1][0][1] = Bp + (long)(n0 + sr1) * ldb + sc;
  gS[1][1][0] = Bp + (long)(n0 + 128 + sr0) * ldb + sc;
  gS[1][1][1] = Bp + (long)(n0 + 128 + sr1) * ldb + sc;

#define STAGE(buf, isB, half, tau)                                              \
  do {                                                                          \
    gload16(gS[isB][half][0] + (long)(tau)*64,                                  \
            &L[(((buf)*2 + (isB)) * 2 + (half)) * 8192 + w * 1024]);            \
    gload16(gS[isB][half][1] + (long)(tau)*64,                                  \
            &L[(((buf)*2 + (isB)) * 2 + (half)) * 8192 + w * 1024 + 512]);      \
  } while (0)

  const int rA = lane & 15;
  const int kk0 = (lane >> 4) * 8;
  const int xorv = (rA & 7) * 8;
  const int rB0 = (wn & 1) * 64 + rA;
  const int aB0 = (0 * 4 + wm) * 8192, aB1 = (1 * 4 + wm) * 8192;
  const int bB0 = (0 * 4 + 2 + (wn >> 1)) * 8192, bB1 = (1 * 4 + 2 + (wn >> 1)) * 8192;

#define READ_A(ab, mb)                                                          \
  _Pragma("unroll") for (int q_ = 0; q_ < 4; ++q_)                              \
  _Pragma("unroll") for (int ks_ = 0; ks_ < 2; ++ks_)                           \
      a[q_][ks_] = dsr128(&L[(ab) + ((mb)*16 + q_ * 16 + rA) * 64 +             \
                             ((ks_ * 32 + kk0) ^ xorv)]);
#define READ_B(bb, dst, nb)                                                     \
  _Pragma("unroll") for (int q_ = 0; q_ < 2; ++q_)                              \
  _Pragma("unroll") for (int ks_ = 0; ks_ < 2; ++ks_)                           \
      dst[q_][ks_] = dsr128(&L[(bb) + (rB0 + ((nb) + q_) * 16) * 64 +           \
                               ((ks_ * 32 + kk0) ^ xorv)]);
#define MM(av, bv, cv)                                                          \
  (DT ? __builtin_amdgcn_mfma_f32_16x16x32_f16(                                 \
            __builtin_bit_cast(f16x8, av), __builtin_bit_cast(f16x8, bv), cv,   \
            0, 0, 0)                                                            \
      : __builtin_amdgcn_mfma_f32_16x16x32_bf16(av, bv, cv, 0, 0, 0))
#define QMFMA(mq, nq, bsel)                                                     \
  _Pragma("unroll") for (int m_ = 0; m_ < 4; ++m_)                              \
  _Pragma("unroll") for (int n_ = 0; n_ < 2; ++n_)                              \
  _Pragma("unroll") for (int ks_ = 0; ks_ < 2; ++ks_)                           \
      acc[(mq)*4 + m_][(nq)*2 + n_] =                                           \
          MM(a[m_][ks_], bsel[n_][ks_], acc[(mq)*4 + m_][(nq)*2 + n_]);
#define PHASE_MFMA(mq, nq, bsel) \
  BAR(); LGKM0(); SCHED0(); SETP(1); QMFMA(mq, nq, bsel); SETP(0); BAR();

  f32x4 acc[8][4] = {};
  bf16x8 a[4][2], b01[2][2], b23[2][2];

  STAGE(0, 0, 0, 0); STAGE(0, 0, 1, 0); STAGE(0, 1, 0, 0); STAGE(0, 1, 1, 0);
  STAGE(1, 0, 0, 1); STAGE(1, 0, 1, 1); STAGE(1, 1, 0, 1); STAGE(1, 1, 1, 1);
  asm volatile("s_waitcnt vmcnt(8)" ::: "memory");
  BAR();

  const int NI = K >> 7;  // 2 K-tiles (2*64) per iteration
  for (int i = 0; i < NI; ++i) {
    const int t1 = 2 * i + 1;
    const bool nf = (i + 1 < NI);
    // P1
    READ_A(aB0, 0); READ_B(bB0, b01, 0);
    if (i > 0) STAGE(1, 0, 0, t1);
    PHASE_MFMA(0, 0, b01);
    // P2
    READ_B(bB0, b23, 2);
    if (i > 0) STAGE(1, 0, 1, t1);
    PHASE_MFMA(0, 1, b23);
    // P3
    READ_A(aB0, 4);
    if (nf) STAGE(0, 1, 0, t1 + 1);
    PHASE_MFMA(1, 0, b01);
    // P4
    if (nf) STAGE(0, 1, 1, t1 + 1);
    BAR(); SETP(1); QMFMA(1, 1, b23); SETP(0);
    if (nf) asm volatile("s_waitcnt vmcnt(4)" ::: "memory");
    else    asm volatile("s_waitcnt vmcnt(0)" ::: "memory");
    BAR();
    // P5
    READ_A(aB1, 0); READ_B(bB1, b01, 0);
    if (nf) STAGE(0, 0, 0, t1 + 1);
    PHASE_MFMA(0, 0, b01);
    // P6
    READ_B(bB1, b23, 2);
    if (nf) STAGE(0, 0, 1, t1 + 1);
    PHASE_MFMA(0, 1, b23);
    // P7
    READ_A(aB1, 4);
    if (nf) STAGE(1, 1, 0, t1 + 2);
    PHASE_MFMA(1, 0, b01);
    // P8
    if (nf) STAGE(1, 1, 1, t1 + 2);
    BAR(); SETP(1); QMFMA(1, 1, b23); SETP(0);
    if (nf) asm volatile("s_waitcnt vmcnt(4)" ::: "memory");
    BAR();
  }

  // epilogue: C/D layout col=lane&15, row=(lane>>4)*4+j
  const int row0 = m0 + wm * 128;
  const int col0 = n0 + wn * 64;
  const int cl = lane & 15;
  const int rg = (lane >> 4) * 4;
#pragma unroll
  for (int mi = 0; mi < 8; mi++) {
#pragma unroll
    for (int ni = 0; ni < 4; ni++) {
#pragma unroll
      for (int j = 0; j < 4; j++) {
        const long gm = row0 + mi * 16 + rg + j;
        const int gn = col0 + ni * 16 + cl;
        float val = acc[mi][ni][j];
        if constexpr (EPI == EPI_QKV) {
          // z=0,1 -> q,k bf16 rows; z=2 -> V transposed fp16 into aux (= resid ptr)
          if (z < 2) {
            ((bf16*)Cb)[z * cstr + gm * ldc + gn] = (bf16)val;
          } else {
            f16* vt = (f16*)resid;
            vt[(long)(gm >> 11) * 2097152 + (long)gn * 2048 + (gm & 2047)] = (f16)val;
          }
        } else if constexpr (EPI == EPI_F16) {
          ((f16*)Cb)[z * cstr + gm * ldc + gn] = (f16)val;
        } else if constexpr (EPI == EPI_AOS) {
          ((bf16*)Cb)[z * cstr + gm * ldc + gn] = (bf16)(val * 0.03125f);
        } else if constexpr (EPI == EPI_SWISH) {
          float hv = val + bias[gn];
          ((bf16*)Cb)[z * cstr + gm * ldc + gn] = (bf16)(hv / (1.0f + __expf(-hv)));
        } else {  // EPI_RESID
          ((float*)Cb)[z * cstr + gm * ldc + gn] = val + bias[gn] + resid[gm * (long)ldc + gn];
        }
      }
    }
  }
#undef STAGE
#undef READ_A
#undef READ_B
#undef MM
#undef QMFMA
#undef PHASE_MFMA
}

extern "C" void kernel_launch(void* const* d_in, const int* in_sizes, int n_in,
                              void* d_out, int out_size, void* d_ws, size_t ws_size,
                              hipStream_t stream) {
  const float* x  = (const float*)d_in[0];
  const float* g  = (const float*)d_in[1];
  const float* be = (const float*)d_in[2];
  const float* Wq = (const float*)d_in[3];
  const float* Wk = (const float*)d_in[4];
  const float* Wv = (const float*)d_in[5];
  const float* W1 = (const float*)d_in[6];
  const float* b1 = (const float*)d_in[7];
  const float* W2 = (const float*)d_in[8];
  const float* b2 = (const float*)d_in[9];

  hipFuncSetAttribute((const void*)&gemm8_k<EPI_QKV, 0>,
                      hipFuncAttributeMaxDynamicSharedMemorySize, 131072);
  hipFuncSetAttribute((const void*)&gemm8_k<EPI_F16, 0>,
                      hipFuncAttributeMaxDynamicSharedMemorySize, 131072);
  hipFuncSetAttribute((const void*)&gemm8_k<EPI_AOS, 1>,
                      hipFuncAttributeMaxDynamicSharedMemorySize, 131072);
  hipFuncSetAttribute((const void*)&gemm8_k<EPI_SWISH, 0>,
                      hipFuncAttributeMaxDynamicSharedMemorySize, 131072);
  hipFuncSetAttribute((const void*)&gemm8_k<EPI_RESID, 0>,
                      hipFuncAttributeMaxDynamicSharedMemorySize, 131072);

  // ---- workspace layout (bytes); total exactly 190,840,832 ----
  // [0,33.5M): xn -> scores group (fp16, 4 batches) -> h[0:..]
  // [33.5,67.1M): q -> h      [67.1,100.6M): k -> h
  // [100.6,134.2M): vT fp16 [8][1024][2048] -> h
  // [134.2,167.8M): ao bf16
  // [167.8M,..): wqkvT(6.3M) + w1T(8.4M) + w2T(8.4M)
  char* ws = (char*)d_ws;
  bf16* xn     = (bf16*)(ws + 0);
  f16*  scores = (f16*)(ws + 0);
  bf16* q      = (bf16*)(ws + 33554432);
  bf16* kk     = (bf16*)(ws + 67108864);
  f16*  vT     = (f16*)(ws + 100663296);
  bf16* ao     = (bf16*)(ws + 134217728);
  bf16* wqT    = (bf16*)(ws + 167772160);
  bf16* w1T    = (bf16*)(ws + 174063616);
  bf16* w2T    = (bf16*)(ws + 182452224);
  bf16* h      = (bf16*)(ws + 0);  // [16384][4096] over [0,134.2M)

  tcast_k<<<dim3(32, 32), 256, 0, stream>>>(Wq, wqT, 1024, 1024);
  tcast_k<<<dim3(32, 32), 256, 0, stream>>>(Wk, wqT + 1048576, 1024, 1024);
  tcast_k<<<dim3(32, 32), 256, 0, stream>>>(Wv, wqT + 2097152, 1024, 1024);
  tcast_k<<<dim3(128, 32), 256, 0, stream>>>(W1, w1T, 1024, 4096);
  tcast_k<<<dim3(32, 128), 256, 0, stream>>>(W2, w2T, 4096, 1024);

  ln_k<<<16384, 256, 0, stream>>>(x, g, be, xn);

  // QKV: z=0,1 -> q,k bf16; z=2 -> vT fp16 transposed (aux via resid param)
  gemm8_k<EPI_QKV, 0><<<dim3(4, 64, 3), 512, 131072, stream>>>(
      xn, wqT, q, nullptr, (const float*)vT, 1024, 1024, 1024, 1024,
      0L, 1048576L, 16777216L);

  // attention in 2 groups of 4 batches; scores buffer reused (stream-ordered)
  for (int gi = 0; gi < 2; gi++) {
    const long zb = gi * 4;
    // scores[z] = q[zb+z] @ k[zb+z]^T  (fp16 out, full grid: 256 WGs)
    gemm8_k<EPI_F16, 0><<<dim3(8, 8, 4), 512, 131072, stream>>>(
        q + zb * 2097152, kk + zb * 2097152, scores, nullptr, nullptr,
        1024, 1024, 1024, 2048, 2097152L, 2097152L, 4194304L);
    softmax16_k<<<8192, 256, 0, stream>>>(scores);
    // ao[zb+z] = (probs @ vT[zb+z]^T) * 1/32   (fp16 MFMA)
    gemm8_k<EPI_AOS, 1><<<dim3(4, 8, 4), 512, 131072, stream>>>(
        (const bf16*)scores, (const bf16*)(vT + zb * 2097152), ao + zb * 2097152,
        nullptr, nullptr, 2048, 2048, 2048, 1024, 4194304L, 2097152L, 2097152L);
  }

  // MLP1: h = swish(ao @ W1 + b1)
  gemm8_k<EPI_SWISH, 0><<<dim3(16, 64, 1), 512, 131072, stream>>>(
      ao, w1T, h, b1, nullptr, 1024, 1024, 1024, 4096, 0L, 0L, 0L);
  // MLP2: out = h @ W2 + b2 + x
  gemm8_k<EPI_RESID, 0><<<dim3(4, 64, 1), 512, 131072, stream>>>(
      h, w2T, d_out, b2, x, 4096, 4096, 4096, 1024, 0L, 0L, 0L);
}

// Round 6
// 707.004 us; speedup vs baseline: 2.4120x; 1.1985x over previous
//
#include <hip/hip_runtime.h>

// EncoderBlock: B=8, S=2048, D=1024, H=4096, single-head attn (scale AFTER softmax),
// LN -> QKV -> scores -> softmax*(1/32) -> PV -> MLP(Swish) -> +residual.
// Round 6: MFMA ks-reorder (dependent pairs 8 apart), QKV coalesced V + fp16 transpose,
// single full-GPU PV launch via slab/quarter workspace overlay. WS = 190,840,832 B.
//
// Workspace overlay (byte offsets):
//  [0,33.5M):    xn -> scores_lo (z=0..3 fp16 slabs) -> h rows 0..4095
//  [33.5,67.1M): q -> ao
//  [67.1,100.6M):k -> h rows 4096..8191
//  [100.6,134.2M): vT fp16 -> h rows 8192..12287
//  [134.2,167.8M): vrows fp16 -> scores_hi (z=4..7) -> h rows 12288..16383
//  [167.8M..): wqT/wkT/wvT, w1T, w2T

#define Bb_ 8
#define Ss_ 2048
#define Dd_ 1024
#define Hh_ 4096

typedef __bf16 bf16;
typedef _Float16 f16;
typedef __attribute__((ext_vector_type(8))) __bf16 bf16x8;
typedef __attribute__((ext_vector_type(8))) _Float16 f16x8;
typedef __attribute__((ext_vector_type(4))) __bf16 bf16x4;
typedef __attribute__((ext_vector_type(4))) float f32x4;

enum { EPI_QKV = 0, EPI_F16 = 1, EPI_AOS = 2, EPI_SWISH = 3, EPI_RESID = 4 };

__device__ __forceinline__ void gload16(const bf16* g, bf16* l) {
  __builtin_amdgcn_global_load_lds(
      (const __attribute__((address_space(1))) void*)g,
      (__attribute__((address_space(3))) void*)l, 16, 0, 0);
}

typedef const __attribute__((address_space(3))) bf16 cl_bf16;
__device__ __forceinline__ bf16x8 dsr128(const bf16* p) {
  bf16x8 r;
  asm volatile("ds_read_b128 %0, %1" : "=v"(r) : "v"((cl_bf16*)p));
  return r;
}

#define BAR() __builtin_amdgcn_s_barrier()
#define LGKM0() asm volatile("s_waitcnt lgkmcnt(0)" ::: "memory")
#define SCHED0() __builtin_amdgcn_sched_barrier(0)
#define SETP(x) __builtin_amdgcn_s_setprio(x)

// ---------- transpose-cast: W[K][N] f32 -> WT[N][K] bf16 ----------
__global__ __launch_bounds__(256) void tcast_k(const float* __restrict__ W,
                                               bf16* __restrict__ WT, int K, int N) {
  __shared__ float tile[32][33];
  const int tn0 = blockIdx.x * 32;
  const int tk0 = blockIdx.y * 32;
  const int t = threadIdx.x;
  const int c = t & 31;
  const int r4 = t >> 5;
#pragma unroll
  for (int i = 0; i < 4; i++) {
    int r = r4 + i * 8;
    tile[r][c] = W[(long)(tk0 + r) * N + (tn0 + c)];
  }
  __syncthreads();
#pragma unroll
  for (int i = 0; i < 4; i++) {
    int r = r4 + i * 8;
    WT[(long)(tn0 + r) * K + (tk0 + c)] = (bf16)tile[c][r];
  }
}

// ---------- fp16 transpose: v[z][2048][1024] -> vT[z][1024][2048] ----------
__global__ __launch_bounds__(256) void tbf16_k(const f16* __restrict__ V,
                                               f16* __restrict__ VT) {
  __shared__ f16 tile[64][72];
  const long z = blockIdx.z;
  const int n0 = blockIdx.x * 64;
  const int k0 = blockIdx.y * 64;
  const int t = threadIdx.x;
  const int r = t >> 3;
  const int c = (t & 7) * 8;
  const f16* Vb = V + z * (long)(Ss_ * Dd_);
  f16* VTb = VT + z * (long)(Dd_ * Ss_);
#pragma unroll
  for (int i = 0; i < 2; i++)
    *(f16x8*)&tile[r + i * 32][c] =
        *(const f16x8*)(Vb + (long)(k0 + r + i * 32) * Dd_ + n0 + c);
  __syncthreads();
#pragma unroll
  for (int i = 0; i < 2; i++) {
    const int n = r + i * 32;
    f16x8 ov;
#pragma unroll
    for (int j = 0; j < 8; j++) ov[j] = tile[c + j][n];
    *(f16x8*)(VTb + (long)(n0 + n) * Ss_ + k0 + c) = ov;
  }
}

// ---------- LayerNorm: x[row][1024] f32 -> xn bf16 ----------
__global__ __launch_bounds__(256) void ln_k(const float* __restrict__ x,
                                            const float* __restrict__ gamma,
                                            const float* __restrict__ beta,
                                            bf16* __restrict__ xn) {
  const long row = blockIdx.x;
  const float* xr = x + row * Dd_;
  const int t = threadIdx.x;
  float4 v = *(const float4*)(xr + t * 4);
  float s = v.x + v.y + v.z + v.w;
  float sq = v.x * v.x + v.y * v.y + v.z * v.z + v.w * v.w;
#pragma unroll
  for (int o = 32; o > 0; o >>= 1) {
    s += __shfl_down(s, o);
    sq += __shfl_down(sq, o);
  }
  __shared__ float ls[4], lq[4];
  const int wid = t >> 6;
  if ((t & 63) == 0) { ls[wid] = s; lq[wid] = sq; }
  __syncthreads();
  if (t == 0) {
    float S = ls[0] + ls[1] + ls[2] + ls[3];
    float Q = lq[0] + lq[1] + lq[2] + lq[3];
    float mu = S * (1.0f / Dd_);
    float var = Q * (1.0f / Dd_) - mu * mu;
    ls[0] = mu;
    lq[0] = rsqrtf(var + 1e-5f);
  }
  __syncthreads();
  const float mu = ls[0], rstd = lq[0];
  float4 g = *(const float4*)(gamma + t * 4);
  float4 be = *(const float4*)(beta + t * 4);
  bf16x4 ov;
  ov[0] = (bf16)((v.x - mu) * rstd * g.x + be.x);
  ov[1] = (bf16)((v.y - mu) * rstd * g.y + be.y);
  ov[2] = (bf16)((v.z - mu) * rstd * g.z + be.z);
  ov[3] = (bf16)((v.w - mu) * rstd * g.w + be.w);
  *(bf16x4*)(xn + row * Dd_ + t * 4) = ov;
}

// ---------- softmax: fp16 scores (two slabs) -> fp16 probs (UNSCALED), in place ----------
__global__ __launch_bounds__(256) void softmax16_k(f16* __restrict__ lo,
                                                   f16* __restrict__ hi) {
  const long row = blockIdx.x;
  const long z = row >> 11;
  f16* sr = (z < 4 ? lo + z * 4194304L : hi + (z - 4) * 4194304L) +
            (row & 2047) * (long)Ss_;
  const int t = threadIdx.x;
  f16x8 v = *(const f16x8*)(sr + t * 8);
  float f[8];
#pragma unroll
  for (int j = 0; j < 8; j++) f[j] = (float)v[j];
  float vm = f[0];
#pragma unroll
  for (int j = 1; j < 8; j++) vm = fmaxf(vm, f[j]);
  __shared__ float red[4];
#pragma unroll
  for (int o = 32; o > 0; o >>= 1) vm = fmaxf(vm, __shfl_xor(vm, o));
  const int wid = t >> 6;
  if ((t & 63) == 0) red[wid] = vm;
  __syncthreads();
  vm = fmaxf(fmaxf(red[0], red[1]), fmaxf(red[2], red[3]));
  float e[8], s = 0.f;
#pragma unroll
  for (int j = 0; j < 8; j++) { e[j] = __expf(f[j] - vm); s += e[j]; }
#pragma unroll
  for (int o = 32; o > 0; o >>= 1) s += __shfl_xor(s, o);
  __syncthreads();
  if ((t & 63) == 0) red[wid] = s;
  __syncthreads();
  s = red[0] + red[1] + red[2] + red[3];
  const float rs = 1.0f / s;  // 1/32 applied in PV epilogue
  f16x8 ov;
#pragma unroll
  for (int j = 0; j < 8; j++) ov[j] = (f16)(e[j] * rs);
  *(f16x8*)(sr + t * 8) = ov;
}

// ================= 256x256x64 8-phase GEMM (C = A[M][K] * B[N][K]^T) =================
// DT=0 bf16 MFMA, DT=1 f16 MFMA. See R4/R5 comments for schedule & hazard proof.
// EPI_AOS: A slab-split (z<4 -> Ab, else bias-cast base). EPI_RESID: A from h quarters.
// EPI_SWISH: C to h quarters. QMFMA: ks OUTERMOST so consecutive MFMAs never share acc.
template <int EPI, int DT>
__global__ __launch_bounds__(512, 2) void gemm8_k(
    const bf16* __restrict__ Ab, const bf16* __restrict__ Bbp, void* __restrict__ Cb,
    const float* __restrict__ bias, const float* __restrict__ resid,
    int K, int lda, int ldb, int ldc, long astr, long bstr, long cstr) {
  extern __shared__ bf16 L[];  // 128 KiB
  const int t = threadIdx.x;
  const int lane = t & 63;
  const int w = t >> 6;
  const int wm = w >> 2, wn = w & 3;

  const int gx = gridDim.x;
  const int nwg = gx * gridDim.y;
  const int dd = blockIdx.y * gx + blockIdx.x;
  const int Lid = (dd & 7) * (nwg >> 3) + (dd >> 3);
  const int m0 = (Lid / gx) * 256;
  const int n0 = (Lid % gx) * 256;

  const long z = blockIdx.z;
  const bf16* A;
  if constexpr (EPI == EPI_AOS) {
    A = (z < 4 ? Ab + z * astr : (const bf16*)bias + (z - 4) * astr);
  } else if constexpr (EPI == EPI_RESID) {
    const long qo[4] = {0, 33554432, 50331648, 67108864};  // elem offsets of h quarters
    A = Ab + qo[m0 >> 12] - (long)(m0 & ~4095) * lda;
  } else {
    A = Ab + z * astr;
  }
  const bf16* Bp = Bbp + z * bstr;

  const int sr0 = (w * 2 + 0) * 8 + (lane >> 3);
  const int sr1 = (w * 2 + 1) * 8 + (lane >> 3);
  const int sc = 8 * ((lane & 7) ^ (lane >> 3));
  const bf16* gS[2][2][2];
  gS[0][0][0] = A + (long)(m0 + sr0) * lda + sc;
  gS[0][0][1] = A + (long)(m0 + sr1) * lda + sc;
  gS[0][1][0] = A + (long)(m0 + 128 + sr0) * lda + sc;
  gS[0][1][1] = A + (long)(m0 + 128 + sr1) * lda + sc;
  gS[1][0][0] = Bp + (long)(n0 + sr0) * ldb + sc;
  gS[1][0][1] = Bp + (long)(n0 + sr1) * ldb + sc;
  gS[1][1][0] = Bp + (long)(n0 + 128 + sr0) * ldb + sc;
  gS[1][1][1] = Bp + (long)(n0 + 128 + sr1) * ldb + sc;

#define STAGE(buf, isB, half, tau)                                              \
  do {                                                                          \
    gload16(gS[isB][half][0] + (long)(tau)*64,                                  \
            &L[(((buf)*2 + (isB)) * 2 + (half)) * 8192 + w * 1024]);            \
    gload16(gS[isB][half][1] + (long)(tau)*64,                                  \
            &L[(((buf)*2 + (isB)) * 2 + (half)) * 8192 + w * 1024 + 512]);      \
  } while (0)

  const int rA = lane & 15;
  const int kk0 = (lane >> 4) * 8;
  const int xorv = (rA & 7) * 8;
  const int rB0 = (wn & 1) * 64 + rA;
  const int aB0 = (0 * 4 + wm) * 8192, aB1 = (1 * 4 + wm) * 8192;
  const int bB0 = (0 * 4 + 2 + (wn >> 1)) * 8192, bB1 = (1 * 4 + 2 + (wn >> 1)) * 8192;

#define READ_A(ab, mb)                                                          \
  _Pragma("unroll") for (int q_ = 0; q_ < 4; ++q_)                              \
  _Pragma("unroll") for (int ks_ = 0; ks_ < 2; ++ks_)                           \
      a[q_][ks_] = dsr128(&L[(ab) + ((mb)*16 + q_ * 16 + rA) * 64 +             \
                             ((ks_ * 32 + kk0) ^ xorv)]);
#define READ_B(bb, dst, nb)                                                     \
  _Pragma("unroll") for (int q_ = 0; q_ < 2; ++q_)                              \
  _Pragma("unroll") for (int ks_ = 0; ks_ < 2; ++ks_)                           \
      dst[q_][ks_] = dsr128(&L[(bb) + (rB0 + ((nb) + q_) * 16) * 64 +           \
                               ((ks_ * 32 + kk0) ^ xorv)]);
#define MM(av, bv, cv)                                                          \
  (DT ? __builtin_amdgcn_mfma_f32_16x16x32_f16(                                 \
            __builtin_bit_cast(f16x8, av), __builtin_bit_cast(f16x8, bv), cv,   \
            0, 0, 0)                                                            \
      : __builtin_amdgcn_mfma_f32_16x16x32_bf16(av, bv, cv, 0, 0, 0))
// ks OUTERMOST: consecutive MFMAs hit distinct accumulators (no back-to-back dep)
#define QMFMA(mq, nq, bsel)                                                     \
  _Pragma("unroll") for (int ks_ = 0; ks_ < 2; ++ks_)                           \
  _Pragma("unroll") for (int m_ = 0; m_ < 4; ++m_)                              \
  _Pragma("unroll") for (int n_ = 0; n_ < 2; ++n_)                              \
      acc[(mq)*4 + m_][(nq)*2 + n_] =                                           \
          MM(a[m_][ks_], bsel[n_][ks_], acc[(mq)*4 + m_][(nq)*2 + n_]);
#define PHASE_MFMA(mq, nq, bsel) \
  BAR(); LGKM0(); SCHED0(); SETP(1); QMFMA(mq, nq, bsel); SETP(0); BAR();

  f32x4 acc[8][4] = {};
  bf16x8 a[4][2], b01[2][2], b23[2][2];

  STAGE(0, 0, 0, 0); STAGE(0, 0, 1, 0); STAGE(0, 1, 0, 0); STAGE(0, 1, 1, 0);
  STAGE(1, 0, 0, 1); STAGE(1, 0, 1, 1); STAGE(1, 1, 0, 1); STAGE(1, 1, 1, 1);
  asm volatile("s_waitcnt vmcnt(8)" ::: "memory");
  BAR();

  const int NI = K >> 7;
  for (int i = 0; i < NI; ++i) {
    const int t1 = 2 * i + 1;
    const bool nf = (i + 1 < NI);
    // P1
    READ_A(aB0, 0); READ_B(bB0, b01, 0);
    if (i > 0) STAGE(1, 0, 0, t1);
    PHASE_MFMA(0, 0, b01);
    // P2
    READ_B(bB0, b23, 2);
    if (i > 0) STAGE(1, 0, 1, t1);
    PHASE_MFMA(0, 1, b23);
    // P3
    READ_A(aB0, 4);
    if (nf) STAGE(0, 1, 0, t1 + 1);
    PHASE_MFMA(1, 0, b01);
    // P4
    if (nf) STAGE(0, 1, 1, t1 + 1);
    BAR(); SETP(1); QMFMA(1, 1, b23); SETP(0);
    if (nf) asm volatile("s_waitcnt vmcnt(4)" ::: "memory");
    else    asm volatile("s_waitcnt vmcnt(0)" ::: "memory");
    BAR();
    // P5
    READ_A(aB1, 0); READ_B(bB1, b01, 0);
    if (nf) STAGE(0, 0, 0, t1 + 1);
    PHASE_MFMA(0, 0, b01);
    // P6
    READ_B(bB1, b23, 2);
    if (nf) STAGE(0, 0, 1, t1 + 1);
    PHASE_MFMA(0, 1, b23);
    // P7
    READ_A(aB1, 4);
    if (nf) STAGE(1, 1, 0, t1 + 2);
    PHASE_MFMA(1, 0, b01);
    // P8
    if (nf) STAGE(1, 1, 1, t1 + 2);
    BAR(); SETP(1); QMFMA(1, 1, b23); SETP(0);
    if (nf) asm volatile("s_waitcnt vmcnt(4)" ::: "memory");
    BAR();
  }

  // epilogue: C/D layout col=lane&15, row=(lane>>4)*4+j
  const int row0 = m0 + wm * 128;
  const int col0 = n0 + wn * 64;
  const int cl = lane & 15;
  const int rg = (lane >> 4) * 4;
#pragma unroll
  for (int mi = 0; mi < 8; mi++) {
#pragma unroll
    for (int ni = 0; ni < 4; ni++) {
#pragma unroll
      for (int j = 0; j < 4; j++) {
        const long gm = row0 + mi * 16 + rg + j;
        const int gn = col0 + ni * 16 + cl;
        float val = acc[mi][ni][j];
        if constexpr (EPI == EPI_QKV) {
          if (z < 2) {
            ((bf16*)Cb)[z * cstr + gm * ldc + gn] = (bf16)val;       // q,k
          } else {
            ((f16*)resid)[gm * (long)ldc + gn] = (f16)val;           // v rows fp16
          }
        } else if constexpr (EPI == EPI_F16) {
          ((f16*)Cb)[z * cstr + gm * ldc + gn] = (f16)val;
        } else if constexpr (EPI == EPI_AOS) {
          ((bf16*)Cb)[z * cstr + gm * ldc + gn] = (bf16)(val * 0.03125f);
        } else if constexpr (EPI == EPI_SWISH) {
          const long qoc[4] = {0, 33554432, 50331648, 67108864};
          bf16* hq = (bf16*)Cb + qoc[m0 >> 12];
          float hv = val + bias[gn];
          hq[(long)(gm & 4095) * ldc + gn] = (bf16)(hv / (1.0f + __expf(-hv)));
        } else {  // EPI_RESID
          ((float*)Cb)[gm * (long)ldc + gn] = val + bias[gn] + resid[gm * (long)ldc + gn];
        }
      }
    }
  }
#undef STAGE
#undef READ_A
#undef READ_B
#undef MM
#undef QMFMA
#undef PHASE_MFMA
}

extern "C" void kernel_launch(void* const* d_in, const int* in_sizes, int n_in,
                              void* d_out, int out_size, void* d_ws, size_t ws_size,
                              hipStream_t stream) {
  const float* x  = (const float*)d_in[0];
  const float* g  = (const float*)d_in[1];
  const float* be = (const float*)d_in[2];
  const float* Wq = (const float*)d_in[3];
  const float* Wk = (const float*)d_in[4];
  const float* Wv = (const float*)d_in[5];
  const float* W1 = (const float*)d_in[6];
  const float* b1 = (const float*)d_in[7];
  const float* W2 = (const float*)d_in[8];
  const float* b2 = (const float*)d_in[9];

  hipFuncSetAttribute((const void*)&gemm8_k<EPI_QKV, 0>,
                      hipFuncAttributeMaxDynamicSharedMemorySize, 131072);
  hipFuncSetAttribute((const void*)&gemm8_k<EPI_F16, 0>,
                      hipFuncAttributeMaxDynamicSharedMemorySize, 131072);
  hipFuncSetAttribute((const void*)&gemm8_k<EPI_AOS, 1>,
                      hipFuncAttributeMaxDynamicSharedMemorySize, 131072);
  hipFuncSetAttribute((const void*)&gemm8_k<EPI_SWISH, 0>,
                      hipFuncAttributeMaxDynamicSharedMemorySize, 131072);
  hipFuncSetAttribute((const void*)&gemm8_k<EPI_RESID, 0>,
                      hipFuncAttributeMaxDynamicSharedMemorySize, 131072);

  char* ws = (char*)d_ws;
  bf16* xn        = (bf16*)(ws + 0);
  f16*  scores_lo = (f16*)(ws + 0);            // z=0..3 after xn dies
  bf16* q         = (bf16*)(ws + 33554432);
  bf16* ao        = (bf16*)(ws + 33554432);    // after q dies
  bf16* kk        = (bf16*)(ws + 67108864);
  f16*  vT        = (f16*)(ws + 100663296);
  f16*  vrows     = (f16*)(ws + 134217728);
  f16*  scores_hi = (f16*)(ws + 134217728);    // z=4..7 after vrows dies
  bf16* wqT       = (bf16*)(ws + 167772160);
  bf16* w1T       = (bf16*)(ws + 174063616);
  bf16* w2T       = (bf16*)(ws + 182452224);
  // h quarters (rows 0..4095, 4096.., 8192.., 12288..) at byte offsets
  // {0, 67108864, 100663296, 134217728} — handled inside EPI_SWISH/EPI_RESID.

  tcast_k<<<dim3(32, 32), 256, 0, stream>>>(Wq, wqT, 1024, 1024);
  tcast_k<<<dim3(32, 32), 256, 0, stream>>>(Wk, wqT + 1048576, 1024, 1024);
  tcast_k<<<dim3(32, 32), 256, 0, stream>>>(Wv, wqT + 2097152, 1024, 1024);
  tcast_k<<<dim3(128, 32), 256, 0, stream>>>(W1, w1T, 1024, 4096);
  tcast_k<<<dim3(32, 128), 256, 0, stream>>>(W2, w2T, 4096, 1024);

  ln_k<<<16384, 256, 0, stream>>>(x, g, be, xn);

  // QKV: z=0,1 -> q,k bf16; z=2 -> v rows fp16 (coalesced) via resid ptr
  gemm8_k<EPI_QKV, 0><<<dim3(4, 64, 3), 512, 131072, stream>>>(
      xn, wqT, q, nullptr, (const float*)vrows, 1024, 1024, 1024, 1024,
      0L, 1048576L, 16777216L);

  // v rows -> vT (fp16)
  tbf16_k<<<dim3(16, 32, 8), 256, 0, stream>>>(vrows, vT);

  // scores: two slab launches, each full GPU (256 WGs)
  gemm8_k<EPI_F16, 0><<<dim3(8, 8, 4), 512, 131072, stream>>>(
      q, kk, scores_lo, nullptr, nullptr,
      1024, 1024, 1024, 2048, 2097152L, 2097152L, 4194304L);
  gemm8_k<EPI_F16, 0><<<dim3(8, 8, 4), 512, 131072, stream>>>(
      q + 4L * 2097152, kk + 4L * 2097152, scores_hi, nullptr, nullptr,
      1024, 1024, 1024, 2048, 2097152L, 2097152L, 4194304L);

  softmax16_k<<<16384, 256, 0, stream>>>(scores_lo, scores_hi);

  // PV: single launch over all 8 batches (256 WGs); A slab-split inside kernel
  gemm8_k<EPI_AOS, 1><<<dim3(4, 8, 8), 512, 131072, stream>>>(
      (const bf16*)scores_lo, (const bf16*)vT, ao, (const float*)scores_hi, nullptr,
      2048, 2048, 2048, 1024, 4194304L, 2097152L, 2097152L);

  // MLP1: h (quartered) = swish(ao @ W1 + b1)
  gemm8_k<EPI_SWISH, 0><<<dim3(16, 64, 1), 512, 131072, stream>>>(
      ao, w1T, ws, b1, nullptr, 1024, 1024, 1024, 4096, 0L, 0L, 0L);
  // MLP2: out = h @ W2 + b2 + x  (A from h quarters)
  gemm8_k<EPI_RESID, 0><<<dim3(4, 64, 1), 512, 131072, stream>>>(
      (const bf16*)ws, w2T, d_out, b2, x, 4096, 4096, 4096, 1024, 0L, 0L, 0L);
}